// Round 2
// baseline (965.737 us; speedup 1.0000x reference)
//
#include <hip/hip_runtime.h>

#define NROWS 16384
#define KCODES 8192
#define DDIM 256
#define KSPLIT 8
#define CPB (KCODES / KSPLIT)   // 1024 codes per block
#define MT 128                  // rows per block
#define JT 128                  // codes per inner tile
#define DT 32                   // d-slice per LDS stage

// ws layout (float units):
//   [0, 16384)         Z2[row] = numpy-pairwise |z_row|^2 (bitwise replica)
//   [16384]            loss accumulator
//   [32768, 163840)    pval[KSPLIT][NROWS]
//   [163840, 294912)   pidx[KSPLIT][NROWS] (int32)
//
// out layout (float units):
//   [0, 4194304)       quantized_st
//   [4194304]          vq_loss
//   [4194305, 4210689) indices (as float)

// Bitwise replica of numpy's fp32 pairwise sum of z*z over 256 contiguous
// elements: split 128+128; each 128-block uses 8 stride-8 sequential
// accumulator chains combined ((r0+r1)+(r2+r3))+((r4+r5)+(r6+r7));
// total = S_lo + S_hi. __f*_rn intrinsics defeat -ffp-contract=fast.
__global__ void vq_z2_kernel(const float* __restrict__ z, float* __restrict__ z2,
                             float* __restrict__ loss) {
    const int row = blockIdx.x * 256 + threadIdx.x;
    const float4* z4 = (const float4*)(z + (size_t)row * DDIM);
    float r[2][8];
    #pragma unroll
    for (int h = 0; h < 2; h++)
        #pragma unroll
        for (int k = 0; k < 8; k++) r[h][k] = 0.0f;
    #pragma unroll
    for (int m = 0; m < 64; m++) {
        const float4 v = z4[m];
        const int h = m >> 5;          // which 128-half
        const int b = (m & 31) * 4;    // element base within half
        r[h][(b + 0) & 7] = __fadd_rn(r[h][(b + 0) & 7], __fmul_rn(v.x, v.x));
        r[h][(b + 1) & 7] = __fadd_rn(r[h][(b + 1) & 7], __fmul_rn(v.y, v.y));
        r[h][(b + 2) & 7] = __fadd_rn(r[h][(b + 2) & 7], __fmul_rn(v.z, v.z));
        r[h][(b + 3) & 7] = __fadd_rn(r[h][(b + 3) & 7], __fmul_rn(v.w, v.w));
    }
    float s[2];
    #pragma unroll
    for (int h = 0; h < 2; h++) {
        const float t01 = __fadd_rn(r[h][0], r[h][1]);
        const float t23 = __fadd_rn(r[h][2], r[h][3]);
        const float t45 = __fadd_rn(r[h][4], r[h][5]);
        const float t67 = __fadd_rn(r[h][6], r[h][7]);
        s[h] = __fadd_rn(__fadd_rn(t01, t23), __fadd_rn(t45, t67));
    }
    z2[row] = __fadd_rn(s[0], s[1]);
    if (blockIdx.x == 0 && threadIdx.x == 0) loss[0] = 0.0f;
}

__global__ __launch_bounds__(256) void vq_phase1(const float* __restrict__ z,
                                                 const float* __restrict__ cb,
                                                 const float* __restrict__ Z2,
                                                 float* __restrict__ pval,
                                                 int* __restrict__ pidx) {
    __shared__ float As[DT][MT];   // 16 KB, [d][row] transposed
    __shared__ float Bs[DT][JT];   // 16 KB, [d][code]
    const int tid = threadIdx.x;
    const int tx = tid & 15;       // code group
    const int ty = tid >> 4;       // row group
    const int n0 = blockIdx.x * MT;
    const int jbase = blockIdx.y * CPB;

    // per-thread row set: rl(i) = 4*ty+i (i<4) else 64+4*ty+(i-4)
    float z2r[8];
    #pragma unroll
    for (int i = 0; i < 8; i++) {
        const int rl = (i < 4) ? (4 * ty + i) : (64 + 4 * ty + (i - 4));
        z2r[i] = Z2[n0 + rl];
    }

    float bestv[8];
    int besti[8];
    #pragma unroll
    for (int i = 0; i < 8; i++) { bestv[i] = 3.0e38f; besti[i] = 0x7fffffff; }

    for (int jt = 0; jt < CPB; jt += JT) {
        float acc[8][8];
        #pragma unroll
        for (int i = 0; i < 8; i++)
            #pragma unroll
            for (int j = 0; j < 8; j++) acc[i][j] = 0.0f;

        for (int dt = 0; dt < DDIM; dt += DT) {
            __syncthreads();
            #pragma unroll
            for (int p = 0; p < 4; p++) {
                const int g = tid + p * 256;
                const int row = g >> 3;       // 0..127
                const int seg = g & 7;        // 8 x float4 per row-slice
                const float4 va = *(const float4*)(z + (size_t)(n0 + row) * DDIM + dt + seg * 4);
                As[seg * 4 + 0][row] = va.x;
                As[seg * 4 + 1][row] = va.y;
                As[seg * 4 + 2][row] = va.z;
                As[seg * 4 + 3][row] = va.w;
                const float4 vb = *(const float4*)(cb + (size_t)(jbase + jt + row) * DDIM + dt + seg * 4);
                Bs[seg * 4 + 0][row] = vb.x;
                Bs[seg * 4 + 1][row] = vb.y;
                Bs[seg * 4 + 2][row] = vb.z;
                Bs[seg * 4 + 3][row] = vb.w;
            }
            __syncthreads();
            #pragma unroll 4
            for (int dd = 0; dd < DT; dd++) {
                float a[8], b[8];
                *(float4*)(a)     = *(const float4*)(&As[dd][4 * ty]);
                *(float4*)(a + 4) = *(const float4*)(&As[dd][64 + 4 * ty]);
                *(float4*)(b)     = *(const float4*)(&Bs[dd][4 * tx]);
                *(float4*)(b + 4) = *(const float4*)(&Bs[dd][64 + 4 * tx]);
                #pragma unroll
                for (int i = 0; i < 8; i++)
                    #pragma unroll
                    for (int j = 0; j < 8; j++)
                        acc[i][j] += a[i] * b[j];
            }
        }
        // score = fl(Z2 - 2*dot): replicates np's (|z|^2 - 2G) rounding; the
        // +|w|^2 term is sub-half-ulp of ~256 and is absorbed in the ref too.
        #pragma unroll
        for (int c = 0; c < 8; c++) {
            const int jl = (c < 4) ? (4 * tx + c) : (64 + 4 * tx + (c - 4));
            const int jg = jbase + jt + jl;
            #pragma unroll
            for (int i = 0; i < 8; i++) {
                const float sc = z2r[i] - 2.0f * acc[i][c];
                if (sc < bestv[i] || (sc == bestv[i] && jg < besti[i])) {
                    bestv[i] = sc;
                    besti[i] = jg;
                }
            }
        }
    }

    // cross-tx reduction per row (reuse LDS)
    __syncthreads();
    float* lv = &As[0][0];       // 4096 floats
    int* li = (int*)&Bs[0][0];   // 4096 ints
    #pragma unroll
    for (int i = 0; i < 8; i++) {
        const int rl = (i < 4) ? (4 * ty + i) : (64 + 4 * ty + (i - 4));
        lv[rl * 16 + tx] = bestv[i];
        li[rl * 16 + tx] = besti[i];
    }
    __syncthreads();
    if (tid < MT) {
        float bv = lv[tid * 16];
        int bi = li[tid * 16];
        #pragma unroll
        for (int t = 1; t < 16; t++) {
            const float v = lv[tid * 16 + t];
            const int ix = li[tid * 16 + t];
            if (v < bv || (v == bv && ix < bi)) { bv = v; bi = ix; }
        }
        pval[blockIdx.y * NROWS + n0 + tid] = bv;
        pidx[blockIdx.y * NROWS + n0 + tid] = bi;
    }
}

__global__ void vq_phase2(const float* __restrict__ z, const float* __restrict__ cb,
                          const float* __restrict__ pval, const int* __restrict__ pidx,
                          float* __restrict__ out, float* __restrict__ loss) {
    __shared__ int sidx[64];
    __shared__ float red[256];
    const int t = threadIdx.x;
    const int rowbase = blockIdx.x * 64;
    if (t < 64) {
        const int row = rowbase + t;
        float bv = pval[row];
        int bi = pidx[row];
        #pragma unroll
        for (int s = 1; s < KSPLIT; s++) {
            const float v = pval[s * NROWS + row];
            const int ix = pidx[s * NROWS + row];
            if (v < bv || (v == bv && ix < bi)) { bv = v; bi = ix; }
        }
        sidx[t] = bi;
        out[4194305 + row] = (float)bi;   // indices as float
    }
    __syncthreads();
    const float4* z4 = (const float4*)z;
    const float4* cb4 = (const float4*)cb;
    float4* o4 = (float4*)out;
    float lsum = 0.0f;
    #pragma unroll 4
    for (int k0 = 0; k0 < 16; k0++) {
        const int k = k0 * 256 + t;
        const int rl = k >> 6;
        const int c = k & 63;
        const int row = rowbase + rl;
        const int idx = sidx[rl];
        const float4 zz = z4[(size_t)row * 64 + c];
        const float4 qq = cb4[(size_t)idx * 64 + c];
        float4 st;
        st.x = zz.x + (qq.x - zz.x);   // straight-through, fp32 order preserved
        st.y = zz.y + (qq.y - zz.y);
        st.z = zz.z + (qq.z - zz.z);
        st.w = zz.w + (qq.w - zz.w);
        o4[(size_t)row * 64 + c] = st;
        const float dx = zz.x - qq.x;
        const float dy = zz.y - qq.y;
        const float dz = zz.z - qq.z;
        const float dw = zz.w - qq.w;
        lsum += dx * dx + dy * dy + dz * dz + dw * dw;
    }
    red[t] = lsum;
    __syncthreads();
    for (int s = 128; s > 0; s >>= 1) {
        if (t < s) red[t] += red[t + s];
        __syncthreads();
    }
    if (t == 0) atomicAdd(loss, red[0]);
}

__global__ void vq_phase3(const float* __restrict__ loss, float* __restrict__ out) {
    if (threadIdx.x == 0)
        out[4194304] = 1.25f * (loss[0] * (1.0f / 4194304.0f));  // /2^22 exact
}

extern "C" void kernel_launch(void* const* d_in, const int* in_sizes, int n_in,
                              void* d_out, int out_size, void* d_ws, size_t ws_size,
                              hipStream_t stream) {
    const float* z = (const float*)d_in[0];
    const float* cb = (const float*)d_in[1];
    float* out = (float*)d_out;
    float* ws = (float*)d_ws;
    float* Z2 = ws;
    float* loss = ws + 16384;
    float* pval = ws + 32768;
    int* pidx = (int*)(ws + 163840);

    vq_z2_kernel<<<NROWS / 256, 256, 0, stream>>>(z, Z2, loss);
    vq_phase1<<<dim3(NROWS / MT, KSPLIT), 256, 0, stream>>>(z, cb, Z2, pval, pidx);
    vq_phase2<<<NROWS / 64, 256, 0, stream>>>(z, cb, pval, pidx, out, loss);
    vq_phase3<<<1, 64, 0, stream>>>(loss, out);
}

// Round 3
// 422.972 us; speedup vs baseline: 2.2832x; 2.2832x over previous
//
#include <hip/hip_runtime.h>

#define NROWS 16384
#define KCODES 8192
#define DDIM 256

typedef _Float16 half8_t __attribute__((ext_vector_type(8)));
typedef _Float16 half4_t __attribute__((ext_vector_type(4)));
typedef float f32x4 __attribute__((ext_vector_type(4)));
typedef unsigned long long u64;

// ---------------- MFMA-path ws layout (byte offsets in d_ws) ----------------
// 0        : wh  fp16[KCODES*256]   (4,194,304 B)
// 4194304  : wl  fp16[KCODES*256]
// 8388608  : Z2  f32[16384]
// 8454144  : loss f32[1]
// 8454400  : part u64[64][16384][2] (16,777,216 B)
// 25231616 : cand int2[16384]
// 25362688 : fidx int[16384]
// 25428224 : REQ
#define WSO_WL    4194304
#define WSO_Z2    8388608
#define WSO_LOSS  8454144
#define WSO_PART  8454400
#define WSO_CAND  25231616
#define WSO_FIDX  25362688
#define WS_REQ    25428224
// z-planes live in d_out[0..4194304) floats: zh fp16[16384*256], zl after.

// ---------- shared: bitwise-np pairwise |z|^2 + loss zero ----------
__global__ void vq_z2_kernel(const float* __restrict__ z, float* __restrict__ z2,
                             float* __restrict__ loss) {
    const int row = blockIdx.x * 256 + threadIdx.x;
    const float4* z4 = (const float4*)(z + (size_t)row * DDIM);
    float r[2][8];
    #pragma unroll
    for (int h = 0; h < 2; h++)
        #pragma unroll
        for (int k = 0; k < 8; k++) r[h][k] = 0.0f;
    #pragma unroll
    for (int m = 0; m < 64; m++) {
        const float4 v = z4[m];
        const int h = m >> 5;
        const int b = (m & 31) * 4;
        r[h][(b + 0) & 7] = __fadd_rn(r[h][(b + 0) & 7], __fmul_rn(v.x, v.x));
        r[h][(b + 1) & 7] = __fadd_rn(r[h][(b + 1) & 7], __fmul_rn(v.y, v.y));
        r[h][(b + 2) & 7] = __fadd_rn(r[h][(b + 2) & 7], __fmul_rn(v.z, v.z));
        r[h][(b + 3) & 7] = __fadd_rn(r[h][(b + 3) & 7], __fmul_rn(v.w, v.w));
    }
    float s[2];
    #pragma unroll
    for (int h = 0; h < 2; h++) {
        const float t01 = __fadd_rn(r[h][0], r[h][1]);
        const float t23 = __fadd_rn(r[h][2], r[h][3]);
        const float t45 = __fadd_rn(r[h][4], r[h][5]);
        const float t67 = __fadd_rn(r[h][6], r[h][7]);
        s[h] = __fadd_rn(__fadd_rn(t01, t23), __fadd_rn(t45, t67));
    }
    z2[row] = __fadd_rn(s[0], s[1]);
    if (blockIdx.x == 0 && threadIdx.x == 0) loss[0] = 0.0f;
}

// ---------- fp16 2-way split conversion ----------
__global__ void vq_cvt(const float* __restrict__ src, _Float16* __restrict__ hi,
                       _Float16* __restrict__ lo, float scale) {
    const size_t i = (size_t)blockIdx.x * 256 + threadIdx.x;
    const float4 v = ((const float4*)src)[i];
    const float x0 = v.x * scale, x1 = v.y * scale, x2 = v.z * scale, x3 = v.w * scale;
    const _Float16 h0 = (_Float16)x0, h1 = (_Float16)x1, h2 = (_Float16)x2, h3 = (_Float16)x3;
    const _Float16 l0 = (_Float16)(x0 - (float)h0), l1 = (_Float16)(x1 - (float)h1);
    const _Float16 l2 = (_Float16)(x2 - (float)h2), l3 = (_Float16)(x3 - (float)h3);
    half4_t H = {h0, h1, h2, h3}, L = {l0, l1, l2, l3};
    ((half4_t*)hi)[i] = H;
    ((half4_t*)lo)[i] = L;
}

__device__ __forceinline__ void load_lds16(const void* g, void* l) {
    __builtin_amdgcn_global_load_lds(
        (const __attribute__((address_space(1))) unsigned int*)g,
        (__attribute__((address_space(3))) unsigned int*)l, 16, 0, 0);
}

__device__ __forceinline__ u64 u64min(u64 a, u64 b) { return a < b ? a : b; }

// ---------- MFMA GEMM + fused per-row top-2 ----------
__global__ __launch_bounds__(256) void vq_gemm(const _Float16* __restrict__ zh,
                                               const _Float16* __restrict__ zl,
                                               const _Float16* __restrict__ wh,
                                               const _Float16* __restrict__ wl,
                                               const float* __restrict__ Z2,
                                               u64* __restrict__ part) {
    __shared__ _Float16 Ah[4096], Al[4096], Bh[4096], Bl[4096];  // 128x32 each
    __shared__ float z2s[128];
    __shared__ u64 stw[2][128][2];
    const int tid = threadIdx.x;
    const int wv = tid >> 6, ln = tid & 63;
    const int lo16 = ln & 15, quad = ln >> 4;
    const int wm = wv >> 1, wn = wv & 1;
    const int n0 = blockIdx.x * 128;   // z rows
    const int j0 = blockIdx.y * 128;   // codes

    if (tid < 128) z2s[tid] = Z2[n0 + tid];

    f32x4 acc[4][4];
    #pragma unroll
    for (int mt = 0; mt < 4; mt++)
        #pragma unroll
        for (int nt = 0; nt < 4; nt++) acc[mt][nt] = (f32x4)0.0f;

    for (int ks = 0; ks < 8; ks++) {
        const int kt = ks * 32;
        #pragma unroll
        for (int r = 0; r < 2; r++) {
            const int c = r * 256 + tid;
            const int row = c >> 2, seg = c & 3;
            const size_t ga = (size_t)(n0 + row) * 256 + kt + seg * 8;
            const size_t gb = (size_t)(j0 + row) * 256 + kt + seg * 8;
            const int lb = r * 2048 + wv * 512;  // wave-uniform LDS base (elems)
            load_lds16(zh + ga, &Ah[lb]);
            load_lds16(zl + ga, &Al[lb]);
            load_lds16(wh + gb, &Bh[lb]);
            load_lds16(wl + gb, &Bl[lb]);
        }
        __syncthreads();   // drains vmcnt -> LDS tiles ready
        half8_t af[4][2];
        #pragma unroll
        for (int mt = 0; mt < 4; mt++) {
            const int rb = (wm * 64 + mt * 16 + lo16) * 32 + quad * 8;
            af[mt][0] = *(const half8_t*)&Ah[rb];
            af[mt][1] = *(const half8_t*)&Al[rb];
        }
        #pragma unroll
        for (int nt = 0; nt < 4; nt++) {
            const int cb_ = (wn * 64 + nt * 16 + lo16) * 32 + quad * 8;
            const half8_t bh = *(const half8_t*)&Bh[cb_];
            const half8_t bl = *(const half8_t*)&Bl[cb_];
            #pragma unroll
            for (int mt = 0; mt < 4; mt++) {
                acc[mt][nt] = __builtin_amdgcn_mfma_f32_16x16x32_f16(af[mt][1], bh, acc[mt][nt], 0, 0, 0);
                acc[mt][nt] = __builtin_amdgcn_mfma_f32_16x16x32_f16(af[mt][0], bl, acc[mt][nt], 0, 0, 0);
                acc[mt][nt] = __builtin_amdgcn_mfma_f32_16x16x32_f16(af[mt][0], bh, acc[mt][nt], 0, 0, 0);
            }
        }
        __syncthreads();   // all reads done before next stage overwrites
    }

    // epilogue: score, per-row top-2 over this block's 128 cols
    #pragma unroll
    for (int mt = 0; mt < 4; mt++) {
        #pragma unroll
        for (int rg = 0; rg < 4; rg++) {
            const int rl = wm * 64 + mt * 16 + quad * 4 + rg;
            const float zz = z2s[rl];
            u64 k[4];
            #pragma unroll
            for (int nt = 0; nt < 4; nt++) {
                // acc = dot(z, 8192*w); score = fl(Z2 - acc*2^-12) == np's fl(Z2-2G)
                const float sc = fmaf(acc[mt][nt][rg], -0x1p-12f, zz);
                const unsigned jg = (unsigned)(j0 + wn * 64 + nt * 16 + lo16);
                k[nt] = ((u64)__float_as_uint(sc) << 32) | jg;
            }
            u64 b1 = u64min(k[0], k[1]);
            u64 b2 = (k[0] < k[1]) ? k[1] : k[0];
            if (k[2] < b1) { b2 = b1; b1 = k[2]; } else if (k[2] < b2) b2 = k[2];
            if (k[3] < b1) { b2 = b1; b1 = k[3]; } else if (k[3] < b2) b2 = k[3];
            #pragma unroll
            for (int m = 1; m < 16; m <<= 1) {
                const u64 o1 = __shfl_xor(b1, m, 64);
                const u64 o2 = __shfl_xor(b2, m, 64);
                const bool le = b1 <= o1;
                const u64 t = le ? o1 : b1;
                const u64 s = le ? b2 : o2;
                b1 = le ? b1 : o1;
                b2 = u64min(s, t);
            }
            if (lo16 == 0) { stw[wn][rl][0] = b1; stw[wn][rl][1] = b2; }
        }
    }
    __syncthreads();
    if (tid < 128) {
        const u64 a1 = stw[0][tid][0], a2 = stw[0][tid][1];
        const u64 o1 = stw[1][tid][0], o2 = stw[1][tid][1];
        const bool le = a1 <= o1;
        const u64 t = le ? o1 : a1;
        const u64 s = le ? a2 : o2;
        const u64 c1 = le ? a1 : o1;
        const u64 c2 = u64min(s, t);
        const size_t base = ((size_t)blockIdx.y * NROWS + n0 + tid) * 2;
        part[base] = c1;
        part[base + 1] = c2;
    }
}

// ---------- merge 64 chunk top-2s -> global top-2 per row ----------
__global__ void vq_merge(const u64* __restrict__ part, int2* __restrict__ cand) {
    const int wv = threadIdx.x >> 6, ln = threadIdx.x & 63;
    const int row = blockIdx.x * 4 + wv;
    const u64* p = part + ((size_t)ln * NROWS + row) * 2;
    u64 b1 = p[0], b2 = p[1];
    #pragma unroll
    for (int m = 1; m < 64; m <<= 1) {
        const u64 o1 = __shfl_xor(b1, m, 64);
        const u64 o2 = __shfl_xor(b2, m, 64);
        const bool le = b1 <= o1;
        const u64 t = le ? o1 : b1;
        const u64 s = le ? b2 : o2;
        b1 = le ? b1 : o1;
        b2 = u64min(s, t);
    }
    if (ln == 0)
        cand[row] = make_int2((int)(b1 & 0xffffffffULL), (int)(b2 & 0xffffffffULL));
}

// ---------- exact fp32 rescore of 2 candidates (np-matching chain) ----------
__global__ void vq_rescore(const float* __restrict__ z, const float* __restrict__ cb,
                           const float* __restrict__ Z2, const int2* __restrict__ cand,
                           int* __restrict__ fidx, float* __restrict__ out) {
    const int t = blockIdx.x * 256 + threadIdx.x;
    const int row = t >> 1, c = t & 1;
    const int2 cd = cand[row];
    const int idx = c ? cd.y : cd.x;
    const float4* zr = (const float4*)(z + (size_t)row * DDIM);
    const float4* wr = (const float4*)(cb + (size_t)idx * DDIM);
    float acc = 0.0f;
    for (int d = 0; d < 64; d++) {
        const float4 a = zr[d], b = wr[d];
        acc = fmaf(a.x, b.x, acc); acc = fmaf(a.y, b.y, acc);
        acc = fmaf(a.z, b.z, acc); acc = fmaf(a.w, b.w, acc);
    }
    const float sc = fmaf(acc, -2.0f, Z2[row]);
    const u64 key = ((u64)__float_as_uint(sc) << 32) | (unsigned)idx;
    const u64 o = __shfl_xor(key, 1, 64);
    const u64 best = u64min(key, o);
    if (c == 0) {
        const int fi = (int)(best & 0xffffffffULL);
        fidx[row] = fi;
        out[4194305 + row] = (float)fi;
    }
}

// ---------- gather + ST output + loss (reads final indices) ----------
__global__ void vq_phase2b(const float* __restrict__ z, const float* __restrict__ cb,
                           const int* __restrict__ fidx, float* __restrict__ out,
                           float* __restrict__ loss) {
    __shared__ int sidx[64];
    __shared__ float red[256];
    const int t = threadIdx.x;
    const int rowbase = blockIdx.x * 64;
    if (t < 64) sidx[t] = fidx[rowbase + t];
    __syncthreads();
    const float4* z4 = (const float4*)z;
    const float4* cb4 = (const float4*)cb;
    float4* o4 = (float4*)out;
    float lsum = 0.0f;
    #pragma unroll 4
    for (int k0 = 0; k0 < 16; k0++) {
        const int k = k0 * 256 + t;
        const int rl = k >> 6;
        const int cc = k & 63;
        const int row = rowbase + rl;
        const int idx = sidx[rl];
        const float4 zz = z4[(size_t)row * 64 + cc];
        const float4 qq = cb4[(size_t)idx * 64 + cc];
        float4 st;
        st.x = zz.x + (qq.x - zz.x);
        st.y = zz.y + (qq.y - zz.y);
        st.z = zz.z + (qq.z - zz.z);
        st.w = zz.w + (qq.w - zz.w);
        o4[(size_t)row * 64 + cc] = st;
        const float dx = zz.x - qq.x, dy = zz.y - qq.y;
        const float dz = zz.z - qq.z, dw = zz.w - qq.w;
        lsum += dx * dx + dy * dy + dz * dz + dw * dw;
    }
    red[t] = lsum;
    __syncthreads();
    for (int s = 128; s > 0; s >>= 1) {
        if (t < s) red[t] += red[t + s];
        __syncthreads();
    }
    if (t == 0) atomicAdd(loss, red[0]);
}

__global__ void vq_phase3(const float* __restrict__ loss, float* __restrict__ out) {
    if (threadIdx.x == 0)
        out[4194304] = 1.25f * (loss[0] * (1.0f / 4194304.0f));
}

// ================= fallback (round-2 verbatim VALU path) =================
#define KSPLIT 8
#define CPB (KCODES / KSPLIT)
#define MT 128
#define JT 128
#define DT 32

__global__ __launch_bounds__(256) void vq_phase1_fb(const float* __restrict__ z,
                                                    const float* __restrict__ cb,
                                                    const float* __restrict__ Z2,
                                                    float* __restrict__ pval,
                                                    int* __restrict__ pidx) {
    __shared__ float As[DT][MT];
    __shared__ float Bs[DT][JT];
    const int tid = threadIdx.x;
    const int tx = tid & 15;
    const int ty = tid >> 4;
    const int n0 = blockIdx.x * MT;
    const int jbase = blockIdx.y * CPB;
    float z2r[8];
    #pragma unroll
    for (int i = 0; i < 8; i++) {
        const int rl = (i < 4) ? (4 * ty + i) : (64 + 4 * ty + (i - 4));
        z2r[i] = Z2[n0 + rl];
    }
    float bestv[8];
    int besti[8];
    #pragma unroll
    for (int i = 0; i < 8; i++) { bestv[i] = 3.0e38f; besti[i] = 0x7fffffff; }
    for (int jt = 0; jt < CPB; jt += JT) {
        float acc[8][8];
        #pragma unroll
        for (int i = 0; i < 8; i++)
            #pragma unroll
            for (int j = 0; j < 8; j++) acc[i][j] = 0.0f;
        for (int dt = 0; dt < DDIM; dt += DT) {
            __syncthreads();
            #pragma unroll
            for (int p = 0; p < 4; p++) {
                const int g = tid + p * 256;
                const int row = g >> 3;
                const int seg = g & 7;
                const float4 va = *(const float4*)(z + (size_t)(n0 + row) * DDIM + dt + seg * 4);
                As[seg * 4 + 0][row] = va.x;
                As[seg * 4 + 1][row] = va.y;
                As[seg * 4 + 2][row] = va.z;
                As[seg * 4 + 3][row] = va.w;
                const float4 vb = *(const float4*)(cb + (size_t)(jbase + jt + row) * DDIM + dt + seg * 4);
                Bs[seg * 4 + 0][row] = vb.x;
                Bs[seg * 4 + 1][row] = vb.y;
                Bs[seg * 4 + 2][row] = vb.z;
                Bs[seg * 4 + 3][row] = vb.w;
            }
            __syncthreads();
            #pragma unroll 4
            for (int dd = 0; dd < DT; dd++) {
                float a[8], b[8];
                *(float4*)(a)     = *(const float4*)(&As[dd][4 * ty]);
                *(float4*)(a + 4) = *(const float4*)(&As[dd][64 + 4 * ty]);
                *(float4*)(b)     = *(const float4*)(&Bs[dd][4 * tx]);
                *(float4*)(b + 4) = *(const float4*)(&Bs[dd][64 + 4 * tx]);
                #pragma unroll
                for (int i = 0; i < 8; i++)
                    #pragma unroll
                    for (int j = 0; j < 8; j++)
                        acc[i][j] += a[i] * b[j];
            }
        }
        #pragma unroll
        for (int c = 0; c < 8; c++) {
            const int jl = (c < 4) ? (4 * tx + c) : (64 + 4 * tx + (c - 4));
            const int jg = jbase + jt + jl;
            #pragma unroll
            for (int i = 0; i < 8; i++) {
                const float sc = z2r[i] - 2.0f * acc[i][c];
                if (sc < bestv[i] || (sc == bestv[i] && jg < besti[i])) {
                    bestv[i] = sc;
                    besti[i] = jg;
                }
            }
        }
    }
    __syncthreads();
    float* lv = &As[0][0];
    int* li = (int*)&Bs[0][0];
    #pragma unroll
    for (int i = 0; i < 8; i++) {
        const int rl = (i < 4) ? (4 * ty + i) : (64 + 4 * ty + (i - 4));
        lv[rl * 16 + tx] = bestv[i];
        li[rl * 16 + tx] = besti[i];
    }
    __syncthreads();
    if (tid < MT) {
        float bv = lv[tid * 16];
        int bi = li[tid * 16];
        #pragma unroll
        for (int t = 1; t < 16; t++) {
            const float v = lv[tid * 16 + t];
            const int ix = li[tid * 16 + t];
            if (v < bv || (v == bv && ix < bi)) { bv = v; bi = ix; }
        }
        pval[blockIdx.y * NROWS + n0 + tid] = bv;
        pidx[blockIdx.y * NROWS + n0 + tid] = bi;
    }
}

__global__ void vq_phase2_fb(const float* __restrict__ z, const float* __restrict__ cb,
                             const float* __restrict__ pval, const int* __restrict__ pidx,
                             float* __restrict__ out, float* __restrict__ loss) {
    __shared__ int sidx[64];
    __shared__ float red[256];
    const int t = threadIdx.x;
    const int rowbase = blockIdx.x * 64;
    if (t < 64) {
        const int row = rowbase + t;
        float bv = pval[row];
        int bi = pidx[row];
        #pragma unroll
        for (int s = 1; s < KSPLIT; s++) {
            const float v = pval[s * NROWS + row];
            const int ix = pidx[s * NROWS + row];
            if (v < bv || (v == bv && ix < bi)) { bv = v; bi = ix; }
        }
        sidx[t] = bi;
        out[4194305 + row] = (float)bi;
    }
    __syncthreads();
    const float4* z4 = (const float4*)z;
    const float4* cb4 = (const float4*)cb;
    float4* o4 = (float4*)out;
    float lsum = 0.0f;
    #pragma unroll 4
    for (int k0 = 0; k0 < 16; k0++) {
        const int k = k0 * 256 + t;
        const int rl = k >> 6;
        const int c = k & 63;
        const int row = rowbase + rl;
        const int idx = sidx[rl];
        const float4 zz = z4[(size_t)row * 64 + c];
        const float4 qq = cb4[(size_t)idx * 64 + c];
        float4 st;
        st.x = zz.x + (qq.x - zz.x);
        st.y = zz.y + (qq.y - zz.y);
        st.z = zz.z + (qq.z - zz.z);
        st.w = zz.w + (qq.w - zz.w);
        o4[(size_t)row * 64 + c] = st;
        const float dx = zz.x - qq.x;
        const float dy = zz.y - qq.y;
        const float dz = zz.z - qq.z;
        const float dw = zz.w - qq.w;
        lsum += dx * dx + dy * dy + dz * dz + dw * dw;
    }
    red[t] = lsum;
    __syncthreads();
    for (int s = 128; s > 0; s >>= 1) {
        if (t < s) red[t] += red[t + s];
        __syncthreads();
    }
    if (t == 0) atomicAdd(loss, red[0]);
}

// =========================================================================
extern "C" void kernel_launch(void* const* d_in, const int* in_sizes, int n_in,
                              void* d_out, int out_size, void* d_ws, size_t ws_size,
                              hipStream_t stream) {
    const float* z = (const float*)d_in[0];
    const float* cb = (const float*)d_in[1];
    float* out = (float*)d_out;
    char* wsb = (char*)d_ws;

    if (ws_size >= (size_t)WS_REQ) {
        // ---- MFMA path ----
        _Float16* wh = (_Float16*)wsb;
        _Float16* wl = (_Float16*)(wsb + WSO_WL);
        float* Z2 = (float*)(wsb + WSO_Z2);
        float* loss = (float*)(wsb + WSO_LOSS);
        u64* part = (u64*)(wsb + WSO_PART);
        int2* cand = (int2*)(wsb + WSO_CAND);
        int* fidx = (int*)(wsb + WSO_FIDX);
        _Float16* zh = (_Float16*)d_out;           // scratch in quantized region
        _Float16* zl = zh + (size_t)NROWS * DDIM;  // overwritten by phase2b at end

        vq_z2_kernel<<<NROWS / 256, 256, 0, stream>>>(z, Z2, loss);
        vq_cvt<<<(NROWS * DDIM) / 1024, 256, 0, stream>>>(z, zh, zl, 1.0f);
        vq_cvt<<<(KCODES * DDIM) / 1024, 256, 0, stream>>>(cb, wh, wl, 8192.0f);
        vq_gemm<<<dim3(NROWS / 128, KCODES / 128), 256, 0, stream>>>(zh, zl, wh, wl, Z2, part);
        vq_merge<<<NROWS / 4, 256, 0, stream>>>(part, cand);
        vq_rescore<<<NROWS * 2 / 256, 256, 0, stream>>>(z, cb, Z2, cand, fidx, out);
        vq_phase2b<<<NROWS / 64, 256, 0, stream>>>(z, cb, fidx, out, loss);
        vq_phase3<<<1, 64, 0, stream>>>(loss, out);
    } else {
        // ---- fallback: round-2 VALU path ----
        float* ws = (float*)d_ws;
        float* Z2 = ws;
        float* loss = ws + 16384;
        float* pval = ws + 32768;
        int* pidx = (int*)(ws + 163840);
        vq_z2_kernel<<<NROWS / 256, 256, 0, stream>>>(z, Z2, loss);
        vq_phase1_fb<<<dim3(NROWS / MT, KSPLIT), 256, 0, stream>>>(z, cb, Z2, pval, pidx);
        vq_phase2_fb<<<NROWS / 64, 256, 0, stream>>>(z, cb, pval, pidx, out, loss);
        vq_phase3<<<1, 64, 0, stream>>>(loss, out);
    }
}

// Round 4
// 251.480 us; speedup vs baseline: 3.8402x; 1.6819x over previous
//
#include <hip/hip_runtime.h>

#define NROWS 16384
#define KCODES 8192
#define DDIM 256

typedef _Float16 half8_t __attribute__((ext_vector_type(8)));
typedef _Float16 half4_t __attribute__((ext_vector_type(4)));
typedef float f32x4 __attribute__((ext_vector_type(4)));
typedef unsigned long long u64;
typedef unsigned int u32;

// ---------------- MFMA-path ws layout (byte offsets in d_ws) ----------------
// 0        : wh  fp16[KCODES*256]           (4,194,304 B)
// 4194304  : Z2  f32[16384]                 (65,536 B)
// 4259840  : loss f32[1]                    (256 B pad)
// 4260096  : part u32[8][16384][3]          (1,572,864 B)
// 5832960  : cand int4[16384]               (262,144 B)
// 6095104  : fidx int[16384]                (65,536 B)
#define WSO_Z2   4194304
#define WSO_LOSS 4259840
#define WSO_PART 4260096
#define WSO_CAND 5832960
#define WSO_FIDX 6095104
#define WS_REQ   6160640
// z planes live in d_out[0..4194304) floats: zh fp16[16384*256], zl after
// (exactly 16,777,216 B = the quantized region; overwritten by phase2b last).

__device__ __forceinline__ u32 umin32(u32 a, u32 b) { return a < b ? a : b; }
__device__ __forceinline__ u32 umax32(u32 a, u32 b) { return a > b ? a : b; }
__device__ __forceinline__ u64 u64min(u64 a, u64 b) { return a < b ? a : b; }

__device__ __forceinline__ void load_lds16(const void* g, void* l) {
    __builtin_amdgcn_global_load_lds(
        (const __attribute__((address_space(1))) unsigned int*)g,
        (__attribute__((address_space(3))) unsigned int*)l, 16, 0, 0);
}

// ---------- fused: bitwise-np pairwise |z|^2 + z fp16 hi/lo split ----------
__global__ void vq_z2cvt(const float* __restrict__ z, float* __restrict__ z2,
                         float* __restrict__ loss, _Float16* __restrict__ zh,
                         _Float16* __restrict__ zl) {
    const int tid = threadIdx.x;
    // phase 1: z2 — np pairwise: 2 halves of 128, each 8 stride-8 chains,
    // combined ((r0+r1)+(r2+r3))+((r4+r5)+(r6+r7)), then lo+hi.
    const int lrow = tid >> 4;
    const int l16 = tid & 15;
    const int row = blockIdx.x * 16 + lrow;
    const int h = l16 >> 3, c = l16 & 7;
    const float* p = z + (size_t)row * DDIM + h * 128 + c;
    float s = 0.0f;
    #pragma unroll
    for (int t = 0; t < 16; t++) {
        const float v = p[t * 8];
        s = __fadd_rn(s, __fmul_rn(v, v));
    }
    s = __fadd_rn(s, __shfl_xor(s, 1, 64));
    s = __fadd_rn(s, __shfl_xor(s, 2, 64));
    s = __fadd_rn(s, __shfl_xor(s, 4, 64));
    s = __fadd_rn(s, __shfl_xor(s, 8, 64));
    if (l16 == 0) z2[row] = s;
    if (blockIdx.x == 0 && tid == 0) loss[0] = 0.0f;
    // phase 2: convert block's 16 rows (4096 elems) to hi/lo fp16 planes
    const float4* zb = (const float4*)(z + (size_t)blockIdx.x * 4096);
    half4_t* zhb = (half4_t*)(zh + (size_t)blockIdx.x * 4096);
    half4_t* zlb = (half4_t*)(zl + (size_t)blockIdx.x * 4096);
    #pragma unroll
    for (int i = 0; i < 4; i++) {
        const int e = i * 256 + tid;
        const float4 v = zb[e];
        const _Float16 h0 = (_Float16)v.x, h1 = (_Float16)v.y;
        const _Float16 h2 = (_Float16)v.z, h3 = (_Float16)v.w;
        const half4_t H = {h0, h1, h2, h3};
        const half4_t L = {(_Float16)(v.x - (float)h0), (_Float16)(v.y - (float)h1),
                           (_Float16)(v.z - (float)h2), (_Float16)(v.w - (float)h3)};
        zhb[e] = H;
        zlb[e] = L;
    }
}

// ---------- w -> fp16 single plane, scaled by 8192 (exact pow2) ----------
__global__ void vq_wcvt(const float* __restrict__ cb, _Float16* __restrict__ wh) {
    const size_t i = (size_t)blockIdx.x * 256 + threadIdx.x;
    const float4 v = ((const float4*)cb)[i];
    const half4_t H = {(_Float16)(v.x * 8192.0f), (_Float16)(v.y * 8192.0f),
                       (_Float16)(v.z * 8192.0f), (_Float16)(v.w * 8192.0f)};
    ((half4_t*)wh)[i] = H;
}

// ---------- 2-pass fp16 MFMA GEMM, block 128x1024, fused top-3 filter ----------
// key = ((int(f) - base + 2^18) << 13) | col, f = RN(Z2*65536 - 16*acc):
// the fp32 ulp at 2^23..2^25 (1 or 2) replicates np's fl(Z2-2G) grid rounding
// exactly in both binades; key lex-order == np's (rounded score, index) order.
__global__ __launch_bounds__(256, 2) void vq_gemm(
    const _Float16* __restrict__ zh, const _Float16* __restrict__ zl,
    const _Float16* __restrict__ wh, const float* __restrict__ Z2,
    u32* __restrict__ part) {
    __shared__ _Float16 Ah[4096], Al[4096], Bh[8192];  // 128x32, 128x32, 256x32
    __shared__ u32 sCD[256];          // [row*2] = C bits, [row*2+1] = D
    __shared__ u32 sR[2][128][3];
    const int tid = threadIdx.x;
    const int wv = tid >> 6, ln = tid & 63;
    const int lo16 = ln & 15, quad = ln >> 4;
    const int wm = wv >> 1, wn = wv & 1;
    const int n0 = blockIdx.x * 128;
    const unsigned jb = blockIdx.y * 1024;

    if (tid < 128) {
        const float C = Z2[n0 + tid] * 65536.0f;   // exact (Z2 mult of 2^-16)
        const int base = (int)C;
        sCD[tid * 2] = __float_as_uint(C);
        sCD[tid * 2 + 1] = ((u32)(262144 - base)) << 13;
    }

    const int tq = tid >> 2, ts = tid & 3;
    const size_t aoff0 = (size_t)(n0 + tq) * 256 + ts * 8;
    const size_t aoff1 = (size_t)(n0 + 64 + tq) * 256 + ts * 8;

    u32 b1[16], b2[16], b3[16];
    #pragma unroll
    for (int s = 0; s < 16; s++) { b1[s] = 0xFFFFFFFFu; b2[s] = 0xFFFFFFFFu; b3[s] = 0xFFFFFFFFu; }

    #pragma unroll 1
    for (int jt = 0; jt < 4; jt++) {
        f32x4 acc[4][8];
        #pragma unroll
        for (int mt = 0; mt < 4; mt++)
            #pragma unroll
            for (int nt = 0; nt < 8; nt++) acc[mt][nt] = (f32x4)0.0f;

        const unsigned jtb = jb + jt * 256;
        #pragma unroll 1
        for (int ks = 0; ks < 8; ks++) {
            const int kt = ks * 32;
            __syncthreads();   // prior tile reads complete (also covers sCD)
            load_lds16(zh + aoff0 + kt, &Ah[(wv * 64) * 8]);
            load_lds16(zl + aoff0 + kt, &Al[(wv * 64) * 8]);
            load_lds16(zh + aoff1 + kt, &Ah[(256 + wv * 64) * 8]);
            load_lds16(zl + aoff1 + kt, &Al[(256 + wv * 64) * 8]);
            #pragma unroll
            for (int r = 0; r < 4; r++) {
                const size_t boff = (size_t)(jtb + r * 64 + tq) * 256 + kt + ts * 8;
                load_lds16(wh + boff, &Bh[(r * 256 + wv * 64) * 8]);
            }
            __syncthreads();   // barrier drains vmcnt -> tiles ready
            half8_t ah[4], al[4];
            #pragma unroll
            for (int mt = 0; mt < 4; mt++) {
                const int rb = (wm * 64 + mt * 16 + lo16) * 32 + quad * 8;
                ah[mt] = *(const half8_t*)&Ah[rb];
                al[mt] = *(const half8_t*)&Al[rb];
            }
            #pragma unroll
            for (int nt = 0; nt < 8; nt++) {
                const int cb_ = (wn * 128 + nt * 16 + lo16) * 32 + quad * 8;
                const half8_t bhf = *(const half8_t*)&Bh[cb_];
                #pragma unroll
                for (int mt = 0; mt < 4; mt++) {
                    acc[mt][nt] = __builtin_amdgcn_mfma_f32_16x16x32_f16(al[mt], bhf, acc[mt][nt], 0, 0, 0);
                    acc[mt][nt] = __builtin_amdgcn_mfma_f32_16x16x32_f16(ah[mt], bhf, acc[mt][nt], 0, 0, 0);
                }
            }
        }
        // per-jt epilogue: key + top-3 insert (registers, no barrier)
        const unsigned colb = jtb + wn * 128 + lo16;
        #pragma unroll
        for (int mt = 0; mt < 4; mt++) {
            #pragma unroll
            for (int rg = 0; rg < 4; rg++) {
                const int rl = wm * 64 + mt * 16 + quad * 4 + rg;
                const float C = __uint_as_float(sCD[rl * 2]);
                const u32 D = sCD[rl * 2 + 1];
                const int s = mt * 4 + rg;
                #pragma unroll
                for (int nt = 0; nt < 8; nt++) {
                    const float f = fmaf(acc[mt][nt][rg], -16.0f, C);
                    const u32 key = (((u32)(int)f) << 13) + (D + colb + nt * 16);
                    const u32 m1 = umin32(key, b1[s]);
                    const u32 r1 = umax32(key, b1[s]);
                    const u32 m2 = umin32(r1, b2[s]);
                    const u32 r2 = umax32(r1, b2[s]);
                    b3[s] = umin32(r2, b3[s]);
                    b1[s] = m1; b2[s] = m2;
                }
            }
        }
    }
    // final: 16-lane top-3 reduce per slot, then cross-wn merge
    #pragma unroll
    for (int s = 0; s < 16; s++) {
        u32 x1 = b1[s], x2 = b2[s], x3 = b3[s];
        #pragma unroll
        for (int m = 1; m < 16; m <<= 1) {
            const u32 o1 = __shfl_xor(x1, m, 64);
            const u32 o2 = __shfl_xor(x2, m, 64);
            const u32 o3 = __shfl_xor(x3, m, 64);
            const u32 hi1 = umax32(x1, o1), lo2 = umin32(x2, o2);
            const u32 hi2 = umax32(x2, o2), lo3 = umin32(x3, o3);
            const u32 n1 = umin32(x1, o1);
            const u32 n2 = umin32(hi1, lo2);
            const u32 n3 = umin32(umax32(hi1, lo2), umin32(hi2, lo3));
            x1 = n1; x2 = n2; x3 = n3;
        }
        if (lo16 == 0) {
            const int rl = wm * 64 + (s >> 2) * 16 + quad * 4 + (s & 3);
            sR[wn][rl][0] = x1; sR[wn][rl][1] = x2; sR[wn][rl][2] = x3;
        }
    }
    __syncthreads();
    if (tid < 128) {
        const u32 a1 = sR[0][tid][0], a2 = sR[0][tid][1], a3 = sR[0][tid][2];
        const u32 o1 = sR[1][tid][0], o2 = sR[1][tid][1], o3 = sR[1][tid][2];
        const u32 hi1 = umax32(a1, o1), lo2 = umin32(a2, o2);
        const u32 hi2 = umax32(a2, o2), lo3 = umin32(a3, o3);
        const u32 n1 = umin32(a1, o1);
        const u32 n2 = umin32(hi1, lo2);
        const u32 n3 = umin32(umax32(hi1, lo2), umin32(hi2, lo3));
        const size_t pb = ((size_t)blockIdx.y * NROWS + n0 + tid) * 3;
        part[pb] = n1; part[pb + 1] = n2; part[pb + 2] = n3;
    }
}

// ---------- merge 8 group top-3s -> global top-3 per row ----------
__global__ void vq_merge(const u32* __restrict__ part, int4* __restrict__ cand) {
    const int row = blockIdx.x * 256 + threadIdx.x;
    u32 b1 = 0xFFFFFFFFu, b2 = 0xFFFFFFFFu, b3 = 0xFFFFFFFFu;
    #pragma unroll
    for (int g = 0; g < 8; g++) {
        const size_t p = ((size_t)g * NROWS + row) * 3;
        const u32 o1 = part[p], o2 = part[p + 1], o3 = part[p + 2];
        const u32 hi1 = umax32(b1, o1), lo2 = umin32(b2, o2);
        const u32 hi2 = umax32(b2, o2), lo3 = umin32(b3, o3);
        const u32 n1 = umin32(b1, o1);
        const u32 n2 = umin32(hi1, lo2);
        const u32 n3 = umin32(umax32(hi1, lo2), umin32(hi2, lo3));
        b1 = n1; b2 = n2; b3 = n3;
    }
    cand[row] = make_int4((int)(b1 & 8191u), (int)(b2 & 8191u), (int)(b3 & 8191u), 0);
}

// ---------- exact fp32 rescore of 3 candidates (np-grid replicating) ----------
__global__ void vq_rescore(const float* __restrict__ z, const float* __restrict__ cb,
                           const float* __restrict__ Z2, const int4* __restrict__ cand,
                           int* __restrict__ fidx, float* __restrict__ out) {
    const int t = blockIdx.x * 256 + threadIdx.x;
    const int row = t >> 2, c = t & 3;
    const int4 cd = cand[row];
    const int idx = (c == 0) ? cd.x : ((c == 1) ? cd.y : cd.z);  // c==3 dups cd.z
    const float4* zr = (const float4*)(z + (size_t)row * DDIM);
    const float4* wr = (const float4*)(cb + (size_t)idx * DDIM);
    float acc = 0.0f;
    for (int d = 0; d < 64; d++) {
        const float4 a = zr[d], b = wr[d];
        acc = fmaf(a.x, b.x, acc); acc = fmaf(a.y, b.y, acc);
        acc = fmaf(a.z, b.z, acc); acc = fmaf(a.w, b.w, acc);
    }
    const float sc = fmaf(acc, -2.0f, Z2[row]);   // single-rounded np grid
    u64 key = ((u64)__float_as_uint(sc) << 32) | (unsigned)idx;
    key = u64min(key, __shfl_xor(key, 1, 64));
    key = u64min(key, __shfl_xor(key, 2, 64));
    if (c == 0) {
        const int fi = (int)(key & 0xffffffffULL);
        fidx[row] = fi;
        out[4194305 + row] = (float)fi;
    }
}

// ---------- gather + ST output + loss ----------
__global__ void vq_phase2b(const float* __restrict__ z, const float* __restrict__ cb,
                           const int* __restrict__ fidx, float* __restrict__ out,
                           float* __restrict__ loss) {
    __shared__ int sidx[64];
    __shared__ float red[256];
    const int t = threadIdx.x;
    const int rowbase = blockIdx.x * 64;
    if (t < 64) sidx[t] = fidx[rowbase + t];
    __syncthreads();
    const float4* z4 = (const float4*)z;
    const float4* cb4 = (const float4*)cb;
    float4* o4 = (float4*)out;
    float lsum = 0.0f;
    #pragma unroll 4
    for (int k0 = 0; k0 < 16; k0++) {
        const int k = k0 * 256 + t;
        const int rl = k >> 6;
        const int cc = k & 63;
        const int row = rowbase + rl;
        const int idx = sidx[rl];
        const float4 zz = z4[(size_t)row * 64 + cc];
        const float4 qq = cb4[(size_t)idx * 64 + cc];
        float4 st;
        st.x = zz.x + (qq.x - zz.x);
        st.y = zz.y + (qq.y - zz.y);
        st.z = zz.z + (qq.z - zz.z);
        st.w = zz.w + (qq.w - zz.w);
        o4[(size_t)row * 64 + cc] = st;
        const float dx = zz.x - qq.x, dy = zz.y - qq.y;
        const float dz = zz.z - qq.z, dw = zz.w - qq.w;
        lsum += dx * dx + dy * dy + dz * dz + dw * dw;
    }
    red[t] = lsum;
    __syncthreads();
    for (int s = 128; s > 0; s >>= 1) {
        if (t < s) red[t] += red[t + s];
        __syncthreads();
    }
    if (t == 0) atomicAdd(loss, red[0]);
}

__global__ void vq_phase3(const float* __restrict__ loss, float* __restrict__ out) {
    if (threadIdx.x == 0)
        out[4194304] = 1.25f * (loss[0] * (1.0f / 4194304.0f));
}

// ================= fallback (round-2 verbatim VALU path) =================
#define KSPLIT 8
#define CPB (KCODES / KSPLIT)
#define MT 128
#define JT 128
#define DT 32

__global__ void vq_z2_fb(const float* __restrict__ z, float* __restrict__ z2,
                         float* __restrict__ loss) {
    const int row = blockIdx.x * 256 + threadIdx.x;
    const float4* z4 = (const float4*)(z + (size_t)row * DDIM);
    float r[2][8];
    #pragma unroll
    for (int h = 0; h < 2; h++)
        #pragma unroll
        for (int k = 0; k < 8; k++) r[h][k] = 0.0f;
    #pragma unroll
    for (int m = 0; m < 64; m++) {
        const float4 v = z4[m];
        const int h = m >> 5;
        const int b = (m & 31) * 4;
        r[h][(b + 0) & 7] = __fadd_rn(r[h][(b + 0) & 7], __fmul_rn(v.x, v.x));
        r[h][(b + 1) & 7] = __fadd_rn(r[h][(b + 1) & 7], __fmul_rn(v.y, v.y));
        r[h][(b + 2) & 7] = __fadd_rn(r[h][(b + 2) & 7], __fmul_rn(v.z, v.z));
        r[h][(b + 3) & 7] = __fadd_rn(r[h][(b + 3) & 7], __fmul_rn(v.w, v.w));
    }
    float s[2];
    #pragma unroll
    for (int h = 0; h < 2; h++) {
        const float t01 = __fadd_rn(r[h][0], r[h][1]);
        const float t23 = __fadd_rn(r[h][2], r[h][3]);
        const float t45 = __fadd_rn(r[h][4], r[h][5]);
        const float t67 = __fadd_rn(r[h][6], r[h][7]);
        s[h] = __fadd_rn(__fadd_rn(t01, t23), __fadd_rn(t45, t67));
    }
    z2[row] = __fadd_rn(s[0], s[1]);
    if (blockIdx.x == 0 && threadIdx.x == 0) loss[0] = 0.0f;
}

__global__ __launch_bounds__(256) void vq_phase1_fb(const float* __restrict__ z,
                                                    const float* __restrict__ cb,
                                                    const float* __restrict__ Z2,
                                                    float* __restrict__ pval,
                                                    int* __restrict__ pidx) {
    __shared__ float As[DT][MT];
    __shared__ float Bs[DT][JT];
    const int tid = threadIdx.x;
    const int tx = tid & 15;
    const int ty = tid >> 4;
    const int n0 = blockIdx.x * MT;
    const int jbase = blockIdx.y * CPB;
    float z2r[8];
    #pragma unroll
    for (int i = 0; i < 8; i++) {
        const int rl = (i < 4) ? (4 * ty + i) : (64 + 4 * ty + (i - 4));
        z2r[i] = Z2[n0 + rl];
    }
    float bestv[8];
    int besti[8];
    #pragma unroll
    for (int i = 0; i < 8; i++) { bestv[i] = 3.0e38f; besti[i] = 0x7fffffff; }
    for (int jt = 0; jt < CPB; jt += JT) {
        float acc[8][8];
        #pragma unroll
        for (int i = 0; i < 8; i++)
            #pragma unroll
            for (int j = 0; j < 8; j++) acc[i][j] = 0.0f;
        for (int dt = 0; dt < DDIM; dt += DT) {
            __syncthreads();
            #pragma unroll
            for (int p = 0; p < 4; p++) {
                const int g = tid + p * 256;
                const int row = g >> 3;
                const int seg = g & 7;
                const float4 va = *(const float4*)(z + (size_t)(n0 + row) * DDIM + dt + seg * 4);
                As[seg * 4 + 0][row] = va.x;
                As[seg * 4 + 1][row] = va.y;
                As[seg * 4 + 2][row] = va.z;
                As[seg * 4 + 3][row] = va.w;
                const float4 vb = *(const float4*)(cb + (size_t)(jbase + jt + row) * DDIM + dt + seg * 4);
                Bs[seg * 4 + 0][row] = vb.x;
                Bs[seg * 4 + 1][row] = vb.y;
                Bs[seg * 4 + 2][row] = vb.z;
                Bs[seg * 4 + 3][row] = vb.w;
            }
            __syncthreads();
            #pragma unroll 4
            for (int dd = 0; dd < DT; dd++) {
                float a[8], b[8];
                *(float4*)(a)     = *(const float4*)(&As[dd][4 * ty]);
                *(float4*)(a + 4) = *(const float4*)(&As[dd][64 + 4 * ty]);
                *(float4*)(b)     = *(const float4*)(&Bs[dd][4 * tx]);
                *(float4*)(b + 4) = *(const float4*)(&Bs[dd][64 + 4 * tx]);
                #pragma unroll
                for (int i = 0; i < 8; i++)
                    #pragma unroll
                    for (int j = 0; j < 8; j++)
                        acc[i][j] += a[i] * b[j];
            }
        }
        #pragma unroll
        for (int c = 0; c < 8; c++) {
            const int jl = (c < 4) ? (4 * tx + c) : (64 + 4 * tx + (c - 4));
            const int jg = jbase + jt + jl;
            #pragma unroll
            for (int i = 0; i < 8; i++) {
                const float sc = z2r[i] - 2.0f * acc[i][c];
                if (sc < bestv[i] || (sc == bestv[i] && jg < besti[i])) {
                    bestv[i] = sc;
                    besti[i] = jg;
                }
            }
        }
    }
    __syncthreads();
    float* lv = &As[0][0];
    int* li = (int*)&Bs[0][0];
    #pragma unroll
    for (int i = 0; i < 8; i++) {
        const int rl = (i < 4) ? (4 * ty + i) : (64 + 4 * ty + (i - 4));
        lv[rl * 16 + tx] = bestv[i];
        li[rl * 16 + tx] = besti[i];
    }
    __syncthreads();
    if (tid < MT) {
        float bv = lv[tid * 16];
        int bi = li[tid * 16];
        #pragma unroll
        for (int t = 1; t < 16; t++) {
            const float v = lv[tid * 16 + t];
            const int ix = li[tid * 16 + t];
            if (v < bv || (v == bv && ix < bi)) { bv = v; bi = ix; }
        }
        pval[blockIdx.y * NROWS + n0 + tid] = bv;
        pidx[blockIdx.y * NROWS + n0 + tid] = bi;
    }
}

__global__ void vq_phase2_fb(const float* __restrict__ z, const float* __restrict__ cb,
                             const float* __restrict__ pval, const int* __restrict__ pidx,
                             float* __restrict__ out, float* __restrict__ loss) {
    __shared__ int sidx[64];
    __shared__ float red[256];
    const int t = threadIdx.x;
    const int rowbase = blockIdx.x * 64;
    if (t < 64) {
        const int row = rowbase + t;
        float bv = pval[row];
        int bi = pidx[row];
        #pragma unroll
        for (int s = 1; s < KSPLIT; s++) {
            const float v = pval[s * NROWS + row];
            const int ix = pidx[s * NROWS + row];
            if (v < bv || (v == bv && ix < bi)) { bv = v; bi = ix; }
        }
        sidx[t] = bi;
        out[4194305 + row] = (float)bi;
    }
    __syncthreads();
    const float4* z4 = (const float4*)z;
    const float4* cb4 = (const float4*)cb;
    float4* o4 = (float4*)out;
    float lsum = 0.0f;
    #pragma unroll 4
    for (int k0 = 0; k0 < 16; k0++) {
        const int k = k0 * 256 + t;
        const int rl = k >> 6;
        const int c = k & 63;
        const int row = rowbase + rl;
        const int idx = sidx[rl];
        const float4 zz = z4[(size_t)row * 64 + c];
        const float4 qq = cb4[(size_t)idx * 64 + c];
        float4 st;
        st.x = zz.x + (qq.x - zz.x);
        st.y = zz.y + (qq.y - zz.y);
        st.z = zz.z + (qq.z - zz.z);
        st.w = zz.w + (qq.w - zz.w);
        o4[(size_t)row * 64 + c] = st;
        const float dx = zz.x - qq.x;
        const float dy = zz.y - qq.y;
        const float dz = zz.z - qq.z;
        const float dw = zz.w - qq.w;
        lsum += dx * dx + dy * dy + dz * dz + dw * dw;
    }
    red[t] = lsum;
    __syncthreads();
    for (int s = 128; s > 0; s >>= 1) {
        if (t < s) red[t] += red[t + s];
        __syncthreads();
    }
    if (t == 0) atomicAdd(loss, red[0]);
}

// =========================================================================
extern "C" void kernel_launch(void* const* d_in, const int* in_sizes, int n_in,
                              void* d_out, int out_size, void* d_ws, size_t ws_size,
                              hipStream_t stream) {
    const float* z = (const float*)d_in[0];
    const float* cb = (const float*)d_in[1];
    float* out = (float*)d_out;
    char* wsb = (char*)d_ws;

    if (ws_size >= (size_t)WS_REQ) {
        _Float16* wh = (_Float16*)wsb;
        float* Z2 = (float*)(wsb + WSO_Z2);
        float* loss = (float*)(wsb + WSO_LOSS);
        u32* part = (u32*)(wsb + WSO_PART);
        int4* cand = (int4*)(wsb + WSO_CAND);
        int* fidx = (int*)(wsb + WSO_FIDX);
        _Float16* zh = (_Float16*)d_out;           // scratch in quantized region
        _Float16* zl = zh + (size_t)NROWS * DDIM;  // overwritten by phase2b at end

        vq_z2cvt<<<NROWS / 16, 256, 0, stream>>>(z, Z2, loss, zh, zl);
        vq_wcvt<<<(KCODES * DDIM) / 1024, 256, 0, stream>>>(cb, wh);
        vq_gemm<<<dim3(NROWS / 128, 8), 256, 0, stream>>>(zh, zl, wh, Z2, part);
        vq_merge<<<NROWS / 256, 256, 0, stream>>>(part, cand);
        vq_rescore<<<(NROWS * 4) / 256, 256, 0, stream>>>(z, cb, Z2, cand, fidx, out);
        vq_phase2b<<<NROWS / 64, 256, 0, stream>>>(z, cb, fidx, out, loss);
        vq_phase3<<<1, 64, 0, stream>>>(loss, out);
    } else {
        float* ws = (float*)d_ws;
        float* Z2 = ws;
        float* loss = ws + 16384;
        float* pval = ws + 32768;
        int* pidx = (int*)(ws + 163840);
        vq_z2_fb<<<NROWS / 256, 256, 0, stream>>>(z, Z2, loss);
        vq_phase1_fb<<<dim3(NROWS / MT, KSPLIT), 256, 0, stream>>>(z, cb, Z2, pval, pidx);
        vq_phase2_fb<<<NROWS / 64, 256, 0, stream>>>(z, cb, pval, pidx, out, loss);
        vq_phase3<<<1, 64, 0, stream>>>(loss, out);
    }
}

// Round 5
// 245.614 us; speedup vs baseline: 3.9319x; 1.0239x over previous
//
#include <hip/hip_runtime.h>

#define NROWS 16384
#define KCODES 8192
#define DDIM 256

typedef _Float16 half8_t __attribute__((ext_vector_type(8)));
typedef float f32x4 __attribute__((ext_vector_type(4)));
typedef unsigned long long u64;
typedef unsigned int u32;

// ---------------- MFMA-path ws layout (byte offsets in d_ws) ----------------
// 0        : wht fp16[32][8192][8]  (4,194,304 B)  k-seg-major transposed w
// 4194304  : Z2  f32[16384]
// 4259840  : loss f32[1]
// 4260096  : part u32[8][16384][3]  (1,572,864 B)
#define WSO_Z2   4194304
#define WSO_LOSS 4259840
#define WSO_PART 4260096
#define WS_REQ   5832960
// zht fp16[32][16384][8] (8.4 MB) lives in d_out[0..16.8MB) quantized region;
// overwritten by vq_epi afterwards.

__device__ __forceinline__ u32 umin32(u32 a, u32 b) { return a < b ? a : b; }
__device__ __forceinline__ u32 umax32(u32 a, u32 b) { return a > b ? a : b; }
__device__ __forceinline__ u64 u64min(u64 a, u64 b) { return a < b ? a : b; }

__device__ __forceinline__ void load_lds16(const void* g, void* l) {
    __builtin_amdgcn_global_load_lds(
        (const __attribute__((address_space(1))) unsigned int*)g,
        (__attribute__((address_space(3))) unsigned int*)l, 16, 0, 0);
}

// ---------- fused prep: np-pairwise |z|^2 + transposed fp16 planes ----------
__global__ void vq_prep(const float* __restrict__ z, const float* __restrict__ cb,
                        float* __restrict__ z2, float* __restrict__ loss,
                        _Float16* __restrict__ zht, _Float16* __restrict__ wht) {
    const int tid = threadIdx.x;
    const int rl = tid & 15, s0 = tid >> 4;
    if (blockIdx.x < 1024) {
        const int rb = blockIdx.x * 16;
        // bitwise-np pairwise |z|^2 (verbatim round-4 structure: 2 halves of
        // 128, 8 stride-8 chains, ((r0+r1)+(r2+r3))+((r4+r5)+(r6+r7)), lo+hi)
        {
            const int lrow = tid >> 4, l16 = tid & 15;
            const int row = rb + lrow;
            const int h = l16 >> 3, c = l16 & 7;
            const float* p = z + (size_t)row * DDIM + h * 128 + c;
            float s = 0.0f;
            #pragma unroll
            for (int t = 0; t < 16; t++) {
                const float v = p[t * 8];
                s = __fadd_rn(s, __fmul_rn(v, v));
            }
            s = __fadd_rn(s, __shfl_xor(s, 1, 64));
            s = __fadd_rn(s, __shfl_xor(s, 2, 64));
            s = __fadd_rn(s, __shfl_xor(s, 4, 64));
            s = __fadd_rn(s, __shfl_xor(s, 8, 64));
            if (l16 == 0) z2[row] = s;
        }
        if (blockIdx.x == 0 && tid == 0) loss[0] = 0.0f;
        // z -> fp16, k-seg-major transposed: zht[s][row][8]
        #pragma unroll
        for (int it = 0; it < 2; it++) {
            const int s = s0 + it * 16;
            const float4* zp = (const float4*)(z + (size_t)(rb + rl) * DDIM + s * 8);
            const float4 a = zp[0], b = zp[1];
            const half8_t H = {(_Float16)a.x, (_Float16)a.y, (_Float16)a.z, (_Float16)a.w,
                               (_Float16)b.x, (_Float16)b.y, (_Float16)b.z, (_Float16)b.w};
            ((half8_t*)zht)[(size_t)s * NROWS + rb + rl] = H;
        }
    } else {
        const int wb = (blockIdx.x - 1024) * 16;
        // w*8192 -> fp16 (exact pow2 scale), transposed: wht[s][code][8]
        #pragma unroll
        for (int it = 0; it < 2; it++) {
            const int s = s0 + it * 16;
            const float4* wp = (const float4*)(cb + (size_t)(wb + rl) * DDIM + s * 8);
            const float4 a = wp[0], b = wp[1];
            const half8_t H = {(_Float16)(a.x * 8192.0f), (_Float16)(a.y * 8192.0f),
                               (_Float16)(a.z * 8192.0f), (_Float16)(a.w * 8192.0f),
                               (_Float16)(b.x * 8192.0f), (_Float16)(b.y * 8192.0f),
                               (_Float16)(b.z * 8192.0f), (_Float16)(b.w * 8192.0f)};
            ((half8_t*)wht)[(size_t)s * KCODES + wb + rl] = H;
        }
    }
}

// ---------- single-pass fp16 MFMA GEMM, 128x1024 block, BK=64 ----------
// key = ((int(f) - base + 2^18) << 13) | col, f = RN(Z2*65536 - 16*acc):
// fp32 ulp of f (1 or 2 at 2^23..2^25) == np's fl(Z2-2G) grid in both
// binades; in-bin order = col order = np first-min tie-break. Per-thread
// top-2 (np winner = global min key, always kept), merged to top-3/row.
__global__ __launch_bounds__(256, 3) void vq_gemm(
    const _Float16* __restrict__ zht, const _Float16* __restrict__ wht,
    const float* __restrict__ Z2, u32* __restrict__ part) {
    __shared__ __align__(16) _Float16 Ah[8192];    // [8 seg][128 row][8]
    __shared__ __align__(16) _Float16 Bh[16384];   // [8 seg][256 code][8]
    __shared__ u32 sR[2][128][3];
    const int tid = threadIdx.x;
    const int wv = tid >> 6, ln = tid & 63;
    const int lo16 = ln & 15, quad = ln >> 4;
    const int wm = wv >> 1, wn = wv & 1;
    const int n0 = blockIdx.x * 128;
    const unsigned jb = blockIdx.y * 1024;

    float Cr[16];
    u32 Dr[16];
    #pragma unroll
    for (int s = 0; s < 16; s++) {
        const int rl = wm * 64 + (s >> 2) * 16 + quad * 4 + (s & 3);
        const float C = Z2[n0 + rl] * 65536.0f;   // exact: mult by 2^16
        Cr[s] = C;
        Dr[s] = ((u32)(262144 - (int)C)) << 13;
    }

    u32 b1[16], b2[16];
    #pragma unroll
    for (int s = 0; s < 16; s++) { b1[s] = 0xFFFFFFFFu; b2[s] = 0xFFFFFFFFu; }

    #pragma unroll 1
    for (int jt = 0; jt < 4; jt++) {
        const unsigned jtb = jb + jt * 256;
        f32x4 acc[4][8];
        #pragma unroll
        for (int mt = 0; mt < 4; mt++)
            #pragma unroll
            for (int nt = 0; nt < 8; nt++) acc[mt][nt] = (f32x4)0.0f;

        #pragma unroll 1
        for (int ks = 0; ks < 4; ks++) {
            const int ksg = ks * 8;
            __syncthreads();   // prior-stage frag reads complete
            #pragma unroll
            for (int r = 0; r < 4; r++) {
                const int c = r * 256 + tid;
                const int s = c >> 7, row = c & 127;
                load_lds16(zht + ((size_t)(ksg + s) * NROWS + n0 + row) * 8,
                           &Ah[(size_t)(r * 256 + wv * 64) * 8]);
            }
            #pragma unroll
            for (int r = 0; r < 8; r++) {
                const int c = r * 256 + tid;
                const int s = c >> 8, code = c & 255;
                load_lds16(wht + ((size_t)(ksg + s) * KCODES + jtb + code) * 8,
                           &Bh[(size_t)(r * 256 + wv * 64) * 8]);
            }
            __syncthreads();   // barrier drains vmcnt -> tiles ready
            #pragma unroll
            for (int ksub = 0; ksub < 2; ksub++) {
                half8_t af[4];
                #pragma unroll
                for (int mt = 0; mt < 4; mt++)
                    af[mt] = *(const half8_t*)
                        &Ah[((ksub * 4 + quad) * 128 + wm * 64 + mt * 16 + lo16) * 8];
                #pragma unroll
                for (int nt = 0; nt < 8; nt++) {
                    const half8_t bf = *(const half8_t*)
                        &Bh[((ksub * 4 + quad) * 256 + wn * 128 + nt * 16 + lo16) * 8];
                    #pragma unroll
                    for (int mt = 0; mt < 4; mt++)
                        acc[mt][nt] = __builtin_amdgcn_mfma_f32_16x16x32_f16(
                            af[mt], bf, acc[mt][nt], 0, 0, 0);
                }
            }
        }
        // per-jt epilogue: key + per-thread top-2 insert (3 min/max)
        const unsigned colb = jtb + wn * 128 + lo16;
        #pragma unroll
        for (int mt = 0; mt < 4; mt++) {
            #pragma unroll
            for (int rg = 0; rg < 4; rg++) {
                const int s = mt * 4 + rg;
                const u32 Dc = Dr[s] + colb;
                #pragma unroll
                for (int nt = 0; nt < 8; nt++) {
                    const float f = fmaf(acc[mt][nt][rg], -16.0f, Cr[s]);
                    const u32 key = (((u32)(int)f) << 13) + (Dc + nt * 16);
                    const u32 mx = umax32(key, b1[s]);
                    b1[s] = umin32(key, b1[s]);
                    b2[s] = umin32(mx, b2[s]);
                }
            }
        }
    }

    // 16-lane merge (top-2 pairs -> top-3), then cross-wn, write part
    #pragma unroll
    for (int s = 0; s < 16; s++) {
        u32 x1 = b1[s], x2 = b2[s], x3 = 0xFFFFFFFFu;
        #pragma unroll
        for (int m = 1; m < 16; m <<= 1) {
            const u32 o1 = __shfl_xor(x1, m, 64);
            const u32 o2 = __shfl_xor(x2, m, 64);
            const u32 o3 = __shfl_xor(x3, m, 64);
            const u32 hi1 = umax32(x1, o1), lo2 = umin32(x2, o2);
            const u32 hi2 = umax32(x2, o2), lo3 = umin32(x3, o3);
            const u32 n1 = umin32(x1, o1);
            const u32 n2 = umin32(hi1, lo2);
            const u32 n3 = umin32(umax32(hi1, lo2), umin32(hi2, lo3));
            x1 = n1; x2 = n2; x3 = n3;
        }
        if (lo16 == 0) {
            const int rl = wm * 64 + (s >> 2) * 16 + quad * 4 + (s & 3);
            sR[wn][rl][0] = x1; sR[wn][rl][1] = x2; sR[wn][rl][2] = x3;
        }
    }
    __syncthreads();
    if (tid < 128) {
        const u32 a1 = sR[0][tid][0], a2 = sR[0][tid][1], a3 = sR[0][tid][2];
        const u32 o1 = sR[1][tid][0], o2 = sR[1][tid][1], o3 = sR[1][tid][2];
        const u32 hi1 = umax32(a1, o1), lo2 = umin32(a2, o2);
        const u32 hi2 = umax32(a2, o2), lo3 = umin32(a3, o3);
        const u32 n1 = umin32(a1, o1);
        const u32 n2 = umin32(hi1, lo2);
        const u32 n3 = umin32(umax32(hi1, lo2), umin32(hi2, lo3));
        const size_t pb = ((size_t)blockIdx.y * NROWS + n0 + tid) * 3;
        part[pb] = n1; part[pb + 1] = n2; part[pb + 2] = n3;
    }
}

// ---------- fused epilogue: merge + exact rescore + gather/ST + loss ----------
__global__ void vq_epi(const float* __restrict__ z, const float* __restrict__ cb,
                       const float* __restrict__ Z2, const u32* __restrict__ part,
                       float* __restrict__ out, float* __restrict__ loss) {
    __shared__ int scand[64][4];
    __shared__ int sfin[64];
    __shared__ float red[256];
    const int t = threadIdx.x;
    const int rb = blockIdx.x * 64;
    if (t < 64) {
        const int row = rb + t;
        u32 x1 = 0xFFFFFFFFu, x2 = 0xFFFFFFFFu, x3 = 0xFFFFFFFFu;
        #pragma unroll
        for (int g = 0; g < 8; g++) {
            const size_t p = ((size_t)g * NROWS + row) * 3;
            const u32 o1 = part[p], o2 = part[p + 1], o3 = part[p + 2];
            const u32 hi1 = umax32(x1, o1), lo2 = umin32(x2, o2);
            const u32 hi2 = umax32(x2, o2), lo3 = umin32(x3, o3);
            const u32 n1 = umin32(x1, o1);
            const u32 n2 = umin32(hi1, lo2);
            const u32 n3 = umin32(umax32(hi1, lo2), umin32(hi2, lo3));
            x1 = n1; x2 = n2; x3 = n3;
        }
        scand[t][0] = (int)(x1 & 8191u);
        scand[t][1] = (int)(x2 & 8191u);
        scand[t][2] = (int)(x3 & 8191u);
        scand[t][3] = (int)(x3 & 8191u);
    }
    __syncthreads();
    {
        // exact fp32 rescore of 3 candidates (np-grid replicating chain)
        const int row = rb + (t >> 2), c = t & 3;
        const int idx = scand[t >> 2][c];
        const float4* zr = (const float4*)(z + (size_t)row * DDIM);
        const float4* wr = (const float4*)(cb + (size_t)idx * DDIM);
        float acc = 0.0f;
        for (int d = 0; d < 64; d++) {
            const float4 a = zr[d], b = wr[d];
            acc = fmaf(a.x, b.x, acc); acc = fmaf(a.y, b.y, acc);
            acc = fmaf(a.z, b.z, acc); acc = fmaf(a.w, b.w, acc);
        }
        const float sc = fmaf(acc, -2.0f, Z2[row]);   // single-rounded np grid
        u64 key = ((u64)__float_as_uint(sc) << 32) | (unsigned)idx;
        key = u64min(key, __shfl_xor(key, 1, 64));
        key = u64min(key, __shfl_xor(key, 2, 64));
        if (c == 0) {
            const int fi = (int)(key & 0xffffffffULL);
            sfin[t >> 2] = fi;
            out[4194305 + row] = (float)fi;
        }
    }
    __syncthreads();
    const float4* z4 = (const float4*)z;
    const float4* cb4 = (const float4*)cb;
    float4* o4 = (float4*)out;
    float lsum = 0.0f;
    #pragma unroll 4
    for (int k0 = 0; k0 < 16; k0++) {
        const int k = k0 * 256 + t;
        const int rl = k >> 6;
        const int cc = k & 63;
        const int row = rb + rl;
        const int idx = sfin[rl];
        const float4 zz = z4[(size_t)row * 64 + cc];
        const float4 qq = cb4[(size_t)idx * 64 + cc];
        float4 st;
        st.x = zz.x + (qq.x - zz.x);   // straight-through, fp32 order preserved
        st.y = zz.y + (qq.y - zz.y);
        st.z = zz.z + (qq.z - zz.z);
        st.w = zz.w + (qq.w - zz.w);
        o4[(size_t)row * 64 + cc] = st;
        const float dx = zz.x - qq.x, dy = zz.y - qq.y;
        const float dz = zz.z - qq.z, dw = zz.w - qq.w;
        lsum += dx * dx + dy * dy + dz * dz + dw * dw;
    }
    red[t] = lsum;
    __syncthreads();
    for (int s = 128; s > 0; s >>= 1) {
        if (t < s) red[t] += red[t + s];
        __syncthreads();
    }
    if (t == 0) atomicAdd(loss, red[0]);
}

__global__ void vq_phase3(const float* __restrict__ loss, float* __restrict__ out) {
    if (threadIdx.x == 0)
        out[4194304] = 1.25f * (loss[0] * (1.0f / 4194304.0f));
}

// ================= fallback (round-2 verbatim VALU path) =================
#define KSPLIT 8
#define CPB (KCODES / KSPLIT)
#define MT 128
#define JT 128
#define DT 32

__global__ void vq_z2_fb(const float* __restrict__ z, float* __restrict__ z2,
                         float* __restrict__ loss) {
    const int row = blockIdx.x * 256 + threadIdx.x;
    const float4* z4 = (const float4*)(z + (size_t)row * DDIM);
    float r[2][8];
    #pragma unroll
    for (int h = 0; h < 2; h++)
        #pragma unroll
        for (int k = 0; k < 8; k++) r[h][k] = 0.0f;
    #pragma unroll
    for (int m = 0; m < 64; m++) {
        const float4 v = z4[m];
        const int h = m >> 5;
        const int b = (m & 31) * 4;
        r[h][(b + 0) & 7] = __fadd_rn(r[h][(b + 0) & 7], __fmul_rn(v.x, v.x));
        r[h][(b + 1) & 7] = __fadd_rn(r[h][(b + 1) & 7], __fmul_rn(v.y, v.y));
        r[h][(b + 2) & 7] = __fadd_rn(r[h][(b + 2) & 7], __fmul_rn(v.z, v.z));
        r[h][(b + 3) & 7] = __fadd_rn(r[h][(b + 3) & 7], __fmul_rn(v.w, v.w));
    }
    float s[2];
    #pragma unroll
    for (int h = 0; h < 2; h++) {
        const float t01 = __fadd_rn(r[h][0], r[h][1]);
        const float t23 = __fadd_rn(r[h][2], r[h][3]);
        const float t45 = __fadd_rn(r[h][4], r[h][5]);
        const float t67 = __fadd_rn(r[h][6], r[h][7]);
        s[h] = __fadd_rn(__fadd_rn(t01, t23), __fadd_rn(t45, t67));
    }
    z2[row] = __fadd_rn(s[0], s[1]);
    if (blockIdx.x == 0 && threadIdx.x == 0) loss[0] = 0.0f;
}

__global__ __launch_bounds__(256) void vq_phase1_fb(const float* __restrict__ z,
                                                    const float* __restrict__ cb,
                                                    const float* __restrict__ Z2,
                                                    float* __restrict__ pval,
                                                    int* __restrict__ pidx) {
    __shared__ float As[DT][MT];
    __shared__ float Bs[DT][JT];
    const int tid = threadIdx.x;
    const int tx = tid & 15;
    const int ty = tid >> 4;
    const int n0 = blockIdx.x * MT;
    const int jbase = blockIdx.y * CPB;
    float z2r[8];
    #pragma unroll
    for (int i = 0; i < 8; i++) {
        const int rl = (i < 4) ? (4 * ty + i) : (64 + 4 * ty + (i - 4));
        z2r[i] = Z2[n0 + rl];
    }
    float bestv[8];
    int besti[8];
    #pragma unroll
    for (int i = 0; i < 8; i++) { bestv[i] = 3.0e38f; besti[i] = 0x7fffffff; }
    for (int jt = 0; jt < CPB; jt += JT) {
        float acc[8][8];
        #pragma unroll
        for (int i = 0; i < 8; i++)
            #pragma unroll
            for (int j = 0; j < 8; j++) acc[i][j] = 0.0f;
        for (int dt = 0; dt < DDIM; dt += DT) {
            __syncthreads();
            #pragma unroll
            for (int p = 0; p < 4; p++) {
                const int g = tid + p * 256;
                const int row = g >> 3;
                const int seg = g & 7;
                const float4 va = *(const float4*)(z + (size_t)(n0 + row) * DDIM + dt + seg * 4);
                As[seg * 4 + 0][row] = va.x;
                As[seg * 4 + 1][row] = va.y;
                As[seg * 4 + 2][row] = va.z;
                As[seg * 4 + 3][row] = va.w;
                const float4 vb = *(const float4*)(cb + (size_t)(jbase + jt + row) * DDIM + dt + seg * 4);
                Bs[seg * 4 + 0][row] = vb.x;
                Bs[seg * 4 + 1][row] = vb.y;
                Bs[seg * 4 + 2][row] = vb.z;
                Bs[seg * 4 + 3][row] = vb.w;
            }
            __syncthreads();
            #pragma unroll 4
            for (int dd = 0; dd < DT; dd++) {
                float a[8], b[8];
                *(float4*)(a)     = *(const float4*)(&As[dd][4 * ty]);
                *(float4*)(a + 4) = *(const float4*)(&As[dd][64 + 4 * ty]);
                *(float4*)(b)     = *(const float4*)(&Bs[dd][4 * tx]);
                *(float4*)(b + 4) = *(const float4*)(&Bs[dd][64 + 4 * tx]);
                #pragma unroll
                for (int i = 0; i < 8; i++)
                    #pragma unroll
                    for (int j = 0; j < 8; j++)
                        acc[i][j] += a[i] * b[j];
            }
        }
        #pragma unroll
        for (int c = 0; c < 8; c++) {
            const int jl = (c < 4) ? (4 * tx + c) : (64 + 4 * tx + (c - 4));
            const int jg = jbase + jt + jl;
            #pragma unroll
            for (int i = 0; i < 8; i++) {
                const float sc = z2r[i] - 2.0f * acc[i][c];
                if (sc < bestv[i] || (sc == bestv[i] && jg < besti[i])) {
                    bestv[i] = sc;
                    besti[i] = jg;
                }
            }
        }
    }
    __syncthreads();
    float* lv = &As[0][0];
    int* li = (int*)&Bs[0][0];
    #pragma unroll
    for (int i = 0; i < 8; i++) {
        const int rl = (i < 4) ? (4 * ty + i) : (64 + 4 * ty + (i - 4));
        lv[rl * 16 + tx] = bestv[i];
        li[rl * 16 + tx] = besti[i];
    }
    __syncthreads();
    if (tid < MT) {
        float bv = lv[tid * 16];
        int bi = li[tid * 16];
        #pragma unroll
        for (int t = 1; t < 16; t++) {
            const float v = lv[tid * 16 + t];
            const int ix = li[tid * 16 + t];
            if (v < bv || (v == bv && ix < bi)) { bv = v; bi = ix; }
        }
        pval[blockIdx.y * NROWS + n0 + tid] = bv;
        pidx[blockIdx.y * NROWS + n0 + tid] = bi;
    }
}

__global__ void vq_phase2_fb(const float* __restrict__ z, const float* __restrict__ cb,
                             const float* __restrict__ pval, const int* __restrict__ pidx,
                             float* __restrict__ out, float* __restrict__ loss) {
    __shared__ int sidx[64];
    __shared__ float red[256];
    const int t = threadIdx.x;
    const int rowbase = blockIdx.x * 64;
    if (t < 64) {
        const int row = rowbase + t;
        float bv = pval[row];
        int bi = pidx[row];
        #pragma unroll
        for (int s = 1; s < KSPLIT; s++) {
            const float v = pval[s * NROWS + row];
            const int ix = pidx[s * NROWS + row];
            if (v < bv || (v == bv && ix < bi)) { bv = v; bi = ix; }
        }
        sidx[t] = bi;
        out[4194305 + row] = (float)bi;
    }
    __syncthreads();
    const float4* z4 = (const float4*)z;
    const float4* cb4 = (const float4*)cb;
    float4* o4 = (float4*)out;
    float lsum = 0.0f;
    #pragma unroll 4
    for (int k0 = 0; k0 < 16; k0++) {
        const int k = k0 * 256 + t;
        const int rl = k >> 6;
        const int c = k & 63;
        const int row = rowbase + rl;
        const int idx = sidx[rl];
        const float4 zz = z4[(size_t)row * 64 + c];
        const float4 qq = cb4[(size_t)idx * 64 + c];
        float4 st;
        st.x = zz.x + (qq.x - zz.x);
        st.y = zz.y + (qq.y - zz.y);
        st.z = zz.z + (qq.z - zz.z);
        st.w = zz.w + (qq.w - zz.w);
        o4[(size_t)row * 64 + c] = st;
        const float dx = zz.x - qq.x;
        const float dy = zz.y - qq.y;
        const float dz = zz.z - qq.z;
        const float dw = zz.w - qq.w;
        lsum += dx * dx + dy * dy + dz * dz + dw * dw;
    }
    red[t] = lsum;
    __syncthreads();
    for (int s = 128; s > 0; s >>= 1) {
        if (t < s) red[t] += red[t + s];
        __syncthreads();
    }
    if (t == 0) atomicAdd(loss, red[0]);
}

// =========================================================================
extern "C" void kernel_launch(void* const* d_in, const int* in_sizes, int n_in,
                              void* d_out, int out_size, void* d_ws, size_t ws_size,
                              hipStream_t stream) {
    const float* z = (const float*)d_in[0];
    const float* cb = (const float*)d_in[1];
    float* out = (float*)d_out;
    char* wsb = (char*)d_ws;

    if (ws_size >= (size_t)WS_REQ) {
        _Float16* wht = (_Float16*)wsb;
        float* Z2 = (float*)(wsb + WSO_Z2);
        float* loss = (float*)(wsb + WSO_LOSS);
        u32* part = (u32*)(wsb + WSO_PART);
        _Float16* zht = (_Float16*)d_out;   // scratch in quantized region

        vq_prep<<<1536, 256, 0, stream>>>(z, cb, Z2, loss, zht, wht);
        vq_gemm<<<dim3(NROWS / 128, 8), 256, 0, stream>>>(zht, wht, Z2, part);
        vq_epi<<<NROWS / 64, 256, 0, stream>>>(z, cb, Z2, part, out, loss);
        vq_phase3<<<1, 64, 0, stream>>>(loss, out);
    } else {
        float* ws = (float*)d_ws;
        float* Z2 = ws;
        float* loss = ws + 16384;
        float* pval = ws + 32768;
        int* pidx = (int*)(ws + 163840);
        vq_z2_fb<<<NROWS / 256, 256, 0, stream>>>(z, Z2, loss);
        vq_phase1_fb<<<dim3(NROWS / MT, KSPLIT), 256, 0, stream>>>(z, cb, Z2, pval, pidx);
        vq_phase2_fb<<<NROWS / 64, 256, 0, stream>>>(z, cb, pval, pidx, out, loss);
        vq_phase3<<<1, 64, 0, stream>>>(loss, out);
    }
}

// Round 6
// 183.872 us; speedup vs baseline: 5.2522x; 1.3358x over previous
//
#include <hip/hip_runtime.h>

#define NROWS 16384
#define KCODES 8192
#define DDIM 256

typedef _Float16 half8_t __attribute__((ext_vector_type(8)));
typedef float f32x4 __attribute__((ext_vector_type(4)));
typedef unsigned long long u64;
typedef unsigned int u32;

// ---------------- MFMA-path ws layout (byte offsets in d_ws) ----------------
// 0        : wht fp16[32][8192][8]  (4,194,304 B)  k-seg-major transposed w
// 4194304  : Z2  f32[16384]
// 4259840  : loss f32[1]
// 4260096  : part u32[8][16384][3]  (1,572,864 B)
#define WSO_Z2   4194304
#define WSO_LOSS 4259840
#define WSO_PART 4260096
#define WS_REQ   5832960
// zht fp16[32][16384][8] (8.4 MB) lives in d_out[0..16.8MB) quantized region;
// overwritten by vq_epi afterwards.

__device__ __forceinline__ u32 umin32(u32 a, u32 b) { return a < b ? a : b; }
__device__ __forceinline__ u32 umax32(u32 a, u32 b) { return a > b ? a : b; }
__device__ __forceinline__ u64 u64min(u64 a, u64 b) { return a < b ? a : b; }

__device__ __forceinline__ void load_lds16(const void* g, void* l) {
    __builtin_amdgcn_global_load_lds(
        (const __attribute__((address_space(1))) unsigned int*)g,
        (__attribute__((address_space(3))) unsigned int*)l, 16, 0, 0);
}

// ---------- fused prep: np-pairwise |z|^2 + transposed fp16 planes ----------
__global__ void vq_prep(const float* __restrict__ z, const float* __restrict__ cb,
                        float* __restrict__ z2, float* __restrict__ loss,
                        _Float16* __restrict__ zht, _Float16* __restrict__ wht) {
    const int tid = threadIdx.x;
    const int rl = tid & 15, s0 = tid >> 4;
    if (blockIdx.x < 1024) {
        const int rb = blockIdx.x * 16;
        // bitwise-np pairwise |z|^2: 2 halves of 128, 8 stride-8 chains,
        // ((r0+r1)+(r2+r3))+((r4+r5)+(r6+r7)), then lo+hi.
        {
            const int lrow = tid >> 4, l16 = tid & 15;
            const int row = rb + lrow;
            const int h = l16 >> 3, c = l16 & 7;
            const float* p = z + (size_t)row * DDIM + h * 128 + c;
            float s = 0.0f;
            #pragma unroll
            for (int t = 0; t < 16; t++) {
                const float v = p[t * 8];
                s = __fadd_rn(s, __fmul_rn(v, v));
            }
            s = __fadd_rn(s, __shfl_xor(s, 1, 64));
            s = __fadd_rn(s, __shfl_xor(s, 2, 64));
            s = __fadd_rn(s, __shfl_xor(s, 4, 64));
            s = __fadd_rn(s, __shfl_xor(s, 8, 64));
            if (l16 == 0) z2[row] = s;
        }
        if (blockIdx.x == 0 && tid == 0) loss[0] = 0.0f;
        // z -> fp16, k-seg-major transposed: zht[s][row][8]
        #pragma unroll
        for (int it = 0; it < 2; it++) {
            const int s = s0 + it * 16;
            const float4* zp = (const float4*)(z + (size_t)(rb + rl) * DDIM + s * 8);
            const float4 a = zp[0], b = zp[1];
            const half8_t H = {(_Float16)a.x, (_Float16)a.y, (_Float16)a.z, (_Float16)a.w,
                               (_Float16)b.x, (_Float16)b.y, (_Float16)b.z, (_Float16)b.w};
            ((half8_t*)zht)[(size_t)s * NROWS + rb + rl] = H;
        }
    } else {
        const int wb = (blockIdx.x - 1024) * 16;
        // w*8192 -> fp16 (exact pow2 scale), transposed: wht[s][code][8]
        #pragma unroll
        for (int it = 0; it < 2; it++) {
            const int s = s0 + it * 16;
            const float4* wp = (const float4*)(cb + (size_t)(wb + rl) * DDIM + s * 8);
            const float4 a = wp[0], b = wp[1];
            const half8_t H = {(_Float16)(a.x * 8192.0f), (_Float16)(a.y * 8192.0f),
                               (_Float16)(a.z * 8192.0f), (_Float16)(a.w * 8192.0f),
                               (_Float16)(b.x * 8192.0f), (_Float16)(b.y * 8192.0f),
                               (_Float16)(b.z * 8192.0f), (_Float16)(b.w * 8192.0f)};
            ((half8_t*)wht)[(size_t)s * KCODES + wb + rl] = H;
        }
    }
}

// ---------- single-pass fp16 MFMA GEMM, 128x1024 block, BK=64 ----------
// key = ((int(f) - base + 2^18) << 13) | col, f = RN(Z2*65536 - 16*acc):
// fp32 ulp of f (1 or 2 at 2^23..2^25) == np's fl(Z2-2G) grid in both
// binades; in-bin order = col order = np first-min tie-break. Per-thread
// top-2 (np winner = global min key, always kept), merged to top-3/row.
// launch_bounds(256,2): 256-VGPR budget so acc[4][8] lives in AGPRs with NO
// scratch spill (r5's (256,3) capped at ~170 regs -> 175 MB spill traffic).
__global__ __launch_bounds__(256, 2) void vq_gemm(
    const _Float16* __restrict__ zht, const _Float16* __restrict__ wht,
    const float* __restrict__ Z2, u32* __restrict__ part) {
    __shared__ __align__(16) _Float16 Ah[8192];    // [8 seg][128 row][8]
    __shared__ __align__(16) _Float16 Bh[16384];   // [8 seg][256 code][8]
    __shared__ float sC[128];                      // Z2*65536 per block row
    __shared__ u32 sR[2][128][3];
    const int tid = threadIdx.x;
    const int wv = tid >> 6, ln = tid & 63;
    const int lo16 = ln & 15, quad = ln >> 4;
    const int wm = wv >> 1, wn = wv & 1;
    const int n0 = blockIdx.x * 128;
    const unsigned jb = blockIdx.y * 1024;

    if (tid < 128) sC[tid] = Z2[n0 + tid] * 65536.0f;   // exact: mult by 2^16

    u32 b1[16], b2[16];
    #pragma unroll
    for (int s = 0; s < 16; s++) { b1[s] = 0xFFFFFFFFu; b2[s] = 0xFFFFFFFFu; }

    #pragma unroll 1
    for (int jt = 0; jt < 4; jt++) {
        const unsigned jtb = jb + jt * 256;
        f32x4 acc[4][8];
        #pragma unroll
        for (int mt = 0; mt < 4; mt++)
            #pragma unroll
            for (int nt = 0; nt < 8; nt++) acc[mt][nt] = (f32x4)0.0f;

        #pragma unroll 1
        for (int ks = 0; ks < 4; ks++) {
            const int ksg = ks * 8;
            __syncthreads();   // prior-stage frag reads complete (covers sC too)
            #pragma unroll
            for (int r = 0; r < 4; r++) {
                const int c = r * 256 + tid;
                const int s = c >> 7, row = c & 127;
                load_lds16(zht + ((size_t)(ksg + s) * NROWS + n0 + row) * 8,
                           &Ah[(size_t)(r * 256 + wv * 64) * 8]);
            }
            #pragma unroll
            for (int r = 0; r < 8; r++) {
                const int c = r * 256 + tid;
                const int s = c >> 8, code = c & 255;
                load_lds16(wht + ((size_t)(ksg + s) * KCODES + jtb + code) * 8,
                           &Bh[(size_t)(r * 256 + wv * 64) * 8]);
            }
            __syncthreads();   // barrier drains vmcnt -> tiles ready
            #pragma unroll
            for (int ksub = 0; ksub < 2; ksub++) {
                half8_t af[4];
                #pragma unroll
                for (int mt = 0; mt < 4; mt++)
                    af[mt] = *(const half8_t*)
                        &Ah[((ksub * 4 + quad) * 128 + wm * 64 + mt * 16 + lo16) * 8];
                #pragma unroll
                for (int nt = 0; nt < 8; nt++) {
                    const half8_t bf = *(const half8_t*)
                        &Bh[((ksub * 4 + quad) * 256 + wn * 128 + nt * 16 + lo16) * 8];
                    #pragma unroll
                    for (int mt = 0; mt < 4; mt++)
                        acc[mt][nt] = __builtin_amdgcn_mfma_f32_16x16x32_f16(
                            af[mt], bf, acc[mt][nt], 0, 0, 0);
                }
            }
        }
        // per-jt epilogue: key + per-thread top-2 insert (3 min/max);
        // C from LDS, D recomputed inline (saves 32 VGPRs vs register arrays)
        const unsigned colb = jtb + wn * 128 + lo16;
        #pragma unroll
        for (int mt = 0; mt < 4; mt++) {
            #pragma unroll
            for (int rg = 0; rg < 4; rg++) {
                const int s = mt * 4 + rg;
                const int rl = wm * 64 + mt * 16 + quad * 4 + rg;
                const float C = sC[rl];
                const u32 Dc = (((u32)(262144 - (int)C)) << 13) + colb;
                #pragma unroll
                for (int nt = 0; nt < 8; nt++) {
                    const float f = fmaf(acc[mt][nt][rg], -16.0f, C);
                    const u32 key = (((u32)(int)f) << 13) + (Dc + nt * 16);
                    const u32 mx = umax32(key, b1[s]);
                    b1[s] = umin32(key, b1[s]);
                    b2[s] = umin32(mx, b2[s]);
                }
            }
        }
    }

    // 16-lane merge (top-2 pairs -> top-3), then cross-wn, write part
    #pragma unroll
    for (int s = 0; s < 16; s++) {
        u32 x1 = b1[s], x2 = b2[s], x3 = 0xFFFFFFFFu;
        #pragma unroll
        for (int m = 1; m < 16; m <<= 1) {
            const u32 o1 = __shfl_xor(x1, m, 64);
            const u32 o2 = __shfl_xor(x2, m, 64);
            const u32 o3 = __shfl_xor(x3, m, 64);
            const u32 hi1 = umax32(x1, o1), lo2 = umin32(x2, o2);
            const u32 hi2 = umax32(x2, o2), lo3 = umin32(x3, o3);
            const u32 n1 = umin32(x1, o1);
            const u32 n2 = umin32(hi1, lo2);
            const u32 n3 = umin32(umax32(hi1, lo2), umin32(hi2, lo3));
            x1 = n1; x2 = n2; x3 = n3;
        }
        if (lo16 == 0) {
            const int rl = wm * 64 + (s >> 2) * 16 + quad * 4 + (s & 3);
            sR[wn][rl][0] = x1; sR[wn][rl][1] = x2; sR[wn][rl][2] = x3;
        }
    }
    __syncthreads();
    if (tid < 128) {
        const u32 a1 = sR[0][tid][0], a2 = sR[0][tid][1], a3 = sR[0][tid][2];
        const u32 o1 = sR[1][tid][0], o2 = sR[1][tid][1], o3 = sR[1][tid][2];
        const u32 hi1 = umax32(a1, o1), lo2 = umin32(a2, o2);
        const u32 hi2 = umax32(a2, o2), lo3 = umin32(a3, o3);
        const u32 n1 = umin32(a1, o1);
        const u32 n2 = umin32(hi1, lo2);
        const u32 n3 = umin32(umax32(hi1, lo2), umin32(hi2, lo3));
        const size_t pb = ((size_t)blockIdx.y * NROWS + n0 + tid) * 3;
        part[pb] = n1; part[pb + 1] = n2; part[pb + 2] = n3;
    }
}

// ---------- fused epilogue: merge + exact rescore + gather/ST + loss ----------
__global__ void vq_epi(const float* __restrict__ z, const float* __restrict__ cb,
                       const float* __restrict__ Z2, const u32* __restrict__ part,
                       float* __restrict__ out, float* __restrict__ loss) {
    __shared__ int scand[64][4];
    __shared__ int sfin[64];
    __shared__ float red[256];
    const int t = threadIdx.x;
    const int rb = blockIdx.x * 64;
    if (t < 64) {
        const int row = rb + t;
        u32 x1 = 0xFFFFFFFFu, x2 = 0xFFFFFFFFu, x3 = 0xFFFFFFFFu;
        #pragma unroll
        for (int g = 0; g < 8; g++) {
            const size_t p = ((size_t)g * NROWS + row) * 3;
            const u32 o1 = part[p], o2 = part[p + 1], o3 = part[p + 2];
            const u32 hi1 = umax32(x1, o1), lo2 = umin32(x2, o2);
            const u32 hi2 = umax32(x2, o2), lo3 = umin32(x3, o3);
            const u32 n1 = umin32(x1, o1);
            const u32 n2 = umin32(hi1, lo2);
            const u32 n3 = umin32(umax32(hi1, lo2), umin32(hi2, lo3));
            x1 = n1; x2 = n2; x3 = n3;
        }
        scand[t][0] = (int)(x1 & 8191u);
        scand[t][1] = (int)(x2 & 8191u);
        scand[t][2] = (int)(x3 & 8191u);
        scand[t][3] = (int)(x3 & 8191u);
    }
    __syncthreads();
    {
        // exact fp32 rescore of 3 candidates (np-grid replicating chain)
        const int row = rb + (t >> 2), c = t & 3;
        const int idx = scand[t >> 2][c];
        const float4* zr = (const float4*)(z + (size_t)row * DDIM);
        const float4* wr = (const float4*)(cb + (size_t)idx * DDIM);
        float acc = 0.0f;
        for (int d = 0; d < 64; d++) {
            const float4 a = zr[d], b = wr[d];
            acc = fmaf(a.x, b.x, acc); acc = fmaf(a.y, b.y, acc);
            acc = fmaf(a.z, b.z, acc); acc = fmaf(a.w, b.w, acc);
        }
        const float sc = fmaf(acc, -2.0f, Z2[row]);   // single-rounded np grid
        u64 key = ((u64)__float_as_uint(sc) << 32) | (unsigned)idx;
        key = u64min(key, __shfl_xor(key, 1, 64));
        key = u64min(key, __shfl_xor(key, 2, 64));
        if (c == 0) {
            const int fi = (int)(key & 0xffffffffULL);
            sfin[t >> 2] = fi;
            out[4194305 + row] = (float)fi;
        }
    }
    __syncthreads();
    const float4* z4 = (const float4*)z;
    const float4* cb4 = (const float4*)cb;
    float4* o4 = (float4*)out;
    float lsum = 0.0f;
    #pragma unroll 4
    for (int k0 = 0; k0 < 16; k0++) {
        const int k = k0 * 256 + t;
        const int rl = k >> 6;
        const int cc = k & 63;
        const int row = rb + rl;
        const int idx = sfin[rl];
        const float4 zz = z4[(size_t)row * 64 + cc];
        const float4 qq = cb4[(size_t)idx * 64 + cc];
        float4 st;
        st.x = zz.x + (qq.x - zz.x);   // straight-through, fp32 order preserved
        st.y = zz.y + (qq.y - zz.y);
        st.z = zz.z + (qq.z - zz.z);
        st.w = zz.w + (qq.w - zz.w);
        o4[(size_t)row * 64 + cc] = st;
        const float dx = zz.x - qq.x, dy = zz.y - qq.y;
        const float dz = zz.z - qq.z, dw = zz.w - qq.w;
        lsum += dx * dx + dy * dy + dz * dz + dw * dw;
    }
    red[t] = lsum;
    __syncthreads();
    for (int s = 128; s > 0; s >>= 1) {
        if (t < s) red[t] += red[t + s];
        __syncthreads();
    }
    if (t == 0) atomicAdd(loss, red[0]);
}

__global__ void vq_phase3(const float* __restrict__ loss, float* __restrict__ out) {
    if (threadIdx.x == 0)
        out[4194304] = 1.25f * (loss[0] * (1.0f / 4194304.0f));
}

// ================= fallback (round-2 verbatim VALU path) =================
#define KSPLIT 8
#define CPB (KCODES / KSPLIT)
#define MT 128
#define JT 128
#define DT 32

__global__ void vq_z2_fb(const float* __restrict__ z, float* __restrict__ z2,
                         float* __restrict__ loss) {
    const int row = blockIdx.x * 256 + threadIdx.x;
    const float4* z4 = (const float4*)(z + (size_t)row * DDIM);
    float r[2][8];
    #pragma unroll
    for (int h = 0; h < 2; h++)
        #pragma unroll
        for (int k = 0; k < 8; k++) r[h][k] = 0.0f;
    #pragma unroll
    for (int m = 0; m < 64; m++) {
        const float4 v = z4[m];
        const int h = m >> 5;
        const int b = (m & 31) * 4;
        r[h][(b + 0) & 7] = __fadd_rn(r[h][(b + 0) & 7], __fmul_rn(v.x, v.x));
        r[h][(b + 1) & 7] = __fadd_rn(r[h][(b + 1) & 7], __fmul_rn(v.y, v.y));
        r[h][(b + 2) & 7] = __fadd_rn(r[h][(b + 2) & 7], __fmul_rn(v.z, v.z));
        r[h][(b + 3) & 7] = __fadd_rn(r[h][(b + 3) & 7], __fmul_rn(v.w, v.w));
    }
    float s[2];
    #pragma unroll
    for (int h = 0; h < 2; h++) {
        const float t01 = __fadd_rn(r[h][0], r[h][1]);
        const float t23 = __fadd_rn(r[h][2], r[h][3]);
        const float t45 = __fadd_rn(r[h][4], r[h][5]);
        const float t67 = __fadd_rn(r[h][6], r[h][7]);
        s[h] = __fadd_rn(__fadd_rn(t01, t23), __fadd_rn(t45, t67));
    }
    z2[row] = __fadd_rn(s[0], s[1]);
    if (blockIdx.x == 0 && threadIdx.x == 0) loss[0] = 0.0f;
}

__global__ __launch_bounds__(256) void vq_phase1_fb(const float* __restrict__ z,
                                                    const float* __restrict__ cb,
                                                    const float* __restrict__ Z2,
                                                    float* __restrict__ pval,
                                                    int* __restrict__ pidx) {
    __shared__ float As[DT][MT];
    __shared__ float Bs[DT][JT];
    const int tid = threadIdx.x;
    const int tx = tid & 15;
    const int ty = tid >> 4;
    const int n0 = blockIdx.x * MT;
    const int jbase = blockIdx.y * CPB;
    float z2r[8];
    #pragma unroll
    for (int i = 0; i < 8; i++) {
        const int rl = (i < 4) ? (4 * ty + i) : (64 + 4 * ty + (i - 4));
        z2r[i] = Z2[n0 + rl];
    }
    float bestv[8];
    int besti[8];
    #pragma unroll
    for (int i = 0; i < 8; i++) { bestv[i] = 3.0e38f; besti[i] = 0x7fffffff; }
    for (int jt = 0; jt < CPB; jt += JT) {
        float acc[8][8];
        #pragma unroll
        for (int i = 0; i < 8; i++)
            #pragma unroll
            for (int j = 0; j < 8; j++) acc[i][j] = 0.0f;
        for (int dt = 0; dt < DDIM; dt += DT) {
            __syncthreads();
            #pragma unroll
            for (int p = 0; p < 4; p++) {
                const int g = tid + p * 256;
                const int row = g >> 3;
                const int seg = g & 7;
                const float4 va = *(const float4*)(z + (size_t)(n0 + row) * DDIM + dt + seg * 4);
                As[seg * 4 + 0][row] = va.x;
                As[seg * 4 + 1][row] = va.y;
                As[seg * 4 + 2][row] = va.z;
                As[seg * 4 + 3][row] = va.w;
                const float4 vb = *(const float4*)(cb + (size_t)(jbase + jt + row) * DDIM + dt + seg * 4);
                Bs[seg * 4 + 0][row] = vb.x;
                Bs[seg * 4 + 1][row] = vb.y;
                Bs[seg * 4 + 2][row] = vb.z;
                Bs[seg * 4 + 3][row] = vb.w;
            }
            __syncthreads();
            #pragma unroll 4
            for (int dd = 0; dd < DT; dd++) {
                float a[8], b[8];
                *(float4*)(a)     = *(const float4*)(&As[dd][4 * ty]);
                *(float4*)(a + 4) = *(const float4*)(&As[dd][64 + 4 * ty]);
                *(float4*)(b)     = *(const float4*)(&Bs[dd][4 * tx]);
                *(float4*)(b + 4) = *(const float4*)(&Bs[dd][64 + 4 * tx]);
                #pragma unroll
                for (int i = 0; i < 8; i++)
                    #pragma unroll
                    for (int j = 0; j < 8; j++)
                        acc[i][j] += a[i] * b[j];
            }
        }
        #pragma unroll
        for (int c = 0; c < 8; c++) {
            const int jl = (c < 4) ? (4 * tx + c) : (64 + 4 * tx + (c - 4));
            const int jg = jbase + jt + jl;
            #pragma unroll
            for (int i = 0; i < 8; i++) {
                const float sc = z2r[i] - 2.0f * acc[i][c];
                if (sc < bestv[i] || (sc == bestv[i] && jg < besti[i])) {
                    bestv[i] = sc;
                    besti[i] = jg;
                }
            }
        }
    }
    __syncthreads();
    float* lv = &As[0][0];
    int* li = (int*)&Bs[0][0];
    #pragma unroll
    for (int i = 0; i < 8; i++) {
        const int rl = (i < 4) ? (4 * ty + i) : (64 + 4 * ty + (i - 4));
        lv[rl * 16 + tx] = bestv[i];
        li[rl * 16 + tx] = besti[i];
    }
    __syncthreads();
    if (tid < MT) {
        float bv = lv[tid * 16];
        int bi = li[tid * 16];
        #pragma unroll
        for (int t = 1; t < 16; t++) {
            const float v = lv[tid * 16 + t];
            const int ix = li[tid * 16 + t];
            if (v < bv || (v == bv && ix < bi)) { bv = v; bi = ix; }
        }
        pval[blockIdx.y * NROWS + n0 + tid] = bv;
        pidx[blockIdx.y * NROWS + n0 + tid] = bi;
    }
}

__global__ void vq_phase2_fb(const float* __restrict__ z, const float* __restrict__ cb,
                             const float* __restrict__ pval, const int* __restrict__ pidx,
                             float* __restrict__ out, float* __restrict__ loss) {
    __shared__ int sidx[64];
    __shared__ float red[256];
    const int t = threadIdx.x;
    const int rowbase = blockIdx.x * 64;
    if (t < 64) {
        const int row = rowbase + t;
        float bv = pval[row];
        int bi = pidx[row];
        #pragma unroll
        for (int s = 1; s < KSPLIT; s++) {
            const float v = pval[s * NROWS + row];
            const int ix = pidx[s * NROWS + row];
            if (v < bv || (v == bv && ix < bi)) { bv = v; bi = ix; }
        }
        sidx[t] = bi;
        out[4194305 + row] = (float)bi;
    }
    __syncthreads();
    const float4* z4 = (const float4*)z;
    const float4* cb4 = (const float4*)cb;
    float4* o4 = (float4*)out;
    float lsum = 0.0f;
    #pragma unroll 4
    for (int k0 = 0; k0 < 16; k0++) {
        const int k = k0 * 256 + t;
        const int rl = k >> 6;
        const int c = k & 63;
        const int row = rowbase + rl;
        const int idx = sidx[rl];
        const float4 zz = z4[(size_t)row * 64 + c];
        const float4 qq = cb4[(size_t)idx * 64 + c];
        float4 st;
        st.x = zz.x + (qq.x - zz.x);
        st.y = zz.y + (qq.y - zz.y);
        st.z = zz.z + (qq.z - zz.z);
        st.w = zz.w + (qq.w - zz.w);
        o4[(size_t)row * 64 + c] = st;
        const float dx = zz.x - qq.x;
        const float dy = zz.y - qq.y;
        const float dz = zz.z - qq.z;
        const float dw = zz.w - qq.w;
        lsum += dx * dx + dy * dy + dz * dz + dw * dw;
    }
    red[t] = lsum;
    __syncthreads();
    for (int s = 128; s > 0; s >>= 1) {
        if (t < s) red[t] += red[t + s];
        __syncthreads();
    }
    if (t == 0) atomicAdd(loss, red[0]);
}

// =========================================================================
extern "C" void kernel_launch(void* const* d_in, const int* in_sizes, int n_in,
                              void* d_out, int out_size, void* d_ws, size_t ws_size,
                              hipStream_t stream) {
    const float* z = (const float*)d_in[0];
    const float* cb = (const float*)d_in[1];
    float* out = (float*)d_out;
    char* wsb = (char*)d_ws;

    if (ws_size >= (size_t)WS_REQ) {
        _Float16* wht = (_Float16*)wsb;
        float* Z2 = (float*)(wsb + WSO_Z2);
        float* loss = (float*)(wsb + WSO_LOSS);
        u32* part = (u32*)(wsb + WSO_PART);
        _Float16* zht = (_Float16*)d_out;   // scratch in quantized region

        vq_prep<<<1536, 256, 0, stream>>>(z, cb, Z2, loss, zht, wht);
        vq_gemm<<<dim3(NROWS / 128, 8), 256, 0, stream>>>(zht, wht, Z2, part);
        vq_epi<<<NROWS / 64, 256, 0, stream>>>(z, cb, Z2, part, out, loss);
        vq_phase3<<<1, 64, 0, stream>>>(loss, out);
    } else {
        float* ws = (float*)d_ws;
        float* Z2 = ws;
        float* loss = ws + 16384;
        float* pval = ws + 32768;
        int* pidx = (int*)(ws + 163840);
        vq_z2_fb<<<NROWS / 256, 256, 0, stream>>>(z, Z2, loss);
        vq_phase1_fb<<<dim3(NROWS / MT, KSPLIT), 256, 0, stream>>>(z, cb, Z2, pval, pidx);
        vq_phase2_fb<<<NROWS / 64, 256, 0, stream>>>(z, cb, pval, pidx, out, loss);
        vq_phase3<<<1, 64, 0, stream>>>(loss, out);
    }
}